// Round 1
// baseline (256.820 us; speedup 1.0000x reference)
//
#include <hip/hip_runtime.h>
#include <hip/hip_bf16.h>
#include <math.h>

#define S_LEN 2048
#define HID   2048
#define NH    32
#define NKV   8
#define HD    64
#define QKD   2560   // QK buffer row stride: Q[0:2048] | K[2048:2560]
#define LOG2E 1.44269504f
#define L2THETA_32 0.591611505f   // log2(500000)/32

typedef unsigned short u16;
typedef __attribute__((ext_vector_type(8))) short short8;   // 8 bf16 (MFMA A/B frag)
typedef __attribute__((ext_vector_type(4))) float f32x4;    // MFMA C/D frag

__device__ __forceinline__ u16 f2bf(float x) {
    union { __hip_bfloat16 b; u16 u; } c; c.b = __float2bfloat16(x); return c.u;
}
__device__ __forceinline__ float bf2f(u16 u) {
    union { unsigned int i; float f; } c; c.i = ((unsigned int)u) << 16; return c.f;
}
__device__ __forceinline__ void async_copy16(void* lds, const void* g) {
    __builtin_amdgcn_global_load_lds((const __attribute__((address_space(1))) unsigned int*)g,
                                     (__attribute__((address_space(3))) unsigned int*)lds,
                                     16, 0, 0);
}

// ---------------------------------------------------------------------------
__global__ __launch_bounds__(256)
void cast_bf16(const float* __restrict__ in, u16* __restrict__ out, int n8) {
    int i = blockIdx.x * blockDim.x + threadIdx.x;
    if (i >= n8) return;
    const float4* p = (const float4*)(in + (size_t)i * 8);
    float4 a = p[0], b = p[1];
    short8 o;
    o[0] = f2bf(a.x); o[1] = f2bf(a.y); o[2] = f2bf(a.z); o[3] = f2bf(a.w);
    o[4] = f2bf(b.x); o[5] = f2bf(b.y); o[6] = f2bf(b.z); o[7] = f2bf(b.w);
    *(short8*)(out + (size_t)i * 8) = o;
}

// ---------------------------------------------------------------------------
// All four weight transposes in one dispatch. z selects the weight.
// ---------------------------------------------------------------------------
__global__ __launch_bounds__(256)
void transpose_all(const float* __restrict__ Wq, const float* __restrict__ Wk,
                   const float* __restrict__ Wv, const float* __restrict__ Wo,
                   u16* __restrict__ WqkvT, u16* __restrict__ WoT) {
    const float* W; u16* WT; int Nin, xT;
    switch (blockIdx.z) {
        case 0:  W = Wq; WT = WqkvT;                         Nin = 2048; xT = 64; break;
        case 1:  W = Wk; WT = WqkvT + (size_t)2048 * 2048;   Nin = 512;  xT = 16; break;
        case 2:  W = Wv; WT = WqkvT + (size_t)2560 * 2048;   Nin = 512;  xT = 16; break;
        default: W = Wo; WT = WoT;                           Nin = 2048; xT = 64; break;
    }
    if ((int)blockIdx.x >= xT) return;
    __shared__ float tile[32][33];
    const int tx = threadIdx.x & 31, ty = threadIdx.x >> 5;
    const int x = blockIdx.x * 32 + tx;
#pragma unroll
    for (int j = ty; j < 32; j += 8)
        tile[j][tx] = W[(size_t)(blockIdx.y * 32 + j) * Nin + x];
    __syncthreads();
    const int xo = blockIdx.y * 32 + tx;
#pragma unroll
    for (int j = ty; j < 32; j += 8)
        WT[(size_t)(blockIdx.x * 32 + j) * 2048 + xo] = f2bf(tile[tx][j]);
}

// ---------------------------------------------------------------------------
// Standalone RoPE over Q (hh 0..31) and K (hh 32..39). Q gets 0.125*log2e
// folded in (attention works in the log2 domain and calls exp2 directly).
// ---------------------------------------------------------------------------
__global__ __launch_bounds__(256)
void rope_qk(u16* __restrict__ QK, const int* __restrict__ pos) {
    int idx = blockIdx.x * blockDim.x + threadIdx.x;
    int d = idx & 31;
    int hh = (idx >> 5) % 40;
    int s = idx / (32 * 40);
    if (s >= S_LEN) return;
    float p = (float)pos[s];
    float inv_freq = exp2f(-(float)d * L2THETA_32);   // theta^(-d/32)
    float ang = p * inv_freq;
    float c = cosf(ang), sn = sinf(ang);
    float sc = (hh < 32) ? 0.125f * LOG2E : 1.0f;
    u16* b = QK + (size_t)s * QKD + hh * HD;
    float x0 = bf2f(b[d]), x1 = bf2f(b[d + 32]);
    b[d]      = f2bf((x0 * c - x1 * sn) * sc);
    b[d + 32] = f2bf((x1 * c + x0 * sn) * sc);
}

// ---------------------------------------------------------------------------
// bf16 GEMM (R9): 512 threads / 8 waves, 128x128 tile, BK=32, double-buffered
// LDS with prefetch-in-flight (vmcnt(2) acquire — 2 vm ops per stage at 512
// thr). Wave micro-tile 32x64 (2x4 accs, 8 MFMAs/iter).
// MODE 0: fp32 C (stride N).
// MODE 1: QKV epilogue — cols <2560 -> bf16 QK (stride QKD); cols >=2560 ->
// V written TRANSPOSED to Vt[d][s].
// ---------------------------------------------------------------------------
template<int MODE>
__global__ __launch_bounds__(512)
void gemm_bt(const u16* __restrict__ A, const u16* __restrict__ Bt,
             void* __restrict__ Cv, u16* __restrict__ Vt, int M, int N, int K) {
    __shared__ __attribute__((aligned(16))) u16 As[2][4096];   // 2 x 8KB
    __shared__ __attribute__((aligned(16))) u16 Bs[2][4096];   // 2 x 8KB
    const int t = threadIdx.x;           // 0..511
    const int lane = t & 63;
    const int w = t >> 6;                // 0..7
    const int lm = lane & 15, quad = lane >> 4;
    const int row0 = blockIdx.y * 128, col0 = blockIdx.x * 128;
    const int wr = (w >> 1) * 32, wc = (w & 1) * 64;   // wave = 32 rows x 64 cols

    f32x4 acc[2][4];
#pragma unroll
    for (int i = 0; i < 2; ++i)
#pragma unroll
        for (int j = 0; j < 4; ++j) acc[i][j] = (f32x4){0.f, 0.f, 0.f, 0.f};

    const size_t strideB = (size_t)K * 2;
    const char* Ab = (const char*)(A + (size_t)row0 * K);
    const char* Bb = (const char*)(Bt + (size_t)col0 * K);

    // stage one 128x32 k-tile pair: 2 vm ops per thread (A, B); 512x16B = 8KB
    auto stage = [&](int k0, int buf) {
        const int f = t * 16;
        const int r = f >> 6, cb = f & 63;
        async_copy16((char*)As[buf] + f, Ab + (size_t)r * strideB + k0 * 2 + cb);
        async_copy16((char*)Bs[buf] + f, Bb + (size_t)r * strideB + k0 * 2 + cb);
    };

    const int nk = K >> 5;
    stage(0, 0);
    if (nk > 1) stage(32, 1);

    for (int kk = 0; kk < nk; ++kk) {
        const int cur = kk & 1;
        // acquire: tile kk resident; tile kk+1 (2 ops) may stay in flight
        if (kk + 1 < nk) { asm volatile("s_waitcnt vmcnt(2)\ns_barrier" ::: "memory"); }
        else             { asm volatile("s_waitcnt vmcnt(0)\ns_barrier" ::: "memory"); }

        short8 af[2], bfv[4];
#pragma unroll
        for (int i = 0; i < 2; ++i)
            af[i] = *(const short8*)((const char*)As[cur] + (wr + 16 * i + lm) * 64 + quad * 16);
#pragma unroll
        for (int j = 0; j < 4; ++j)
            bfv[j] = *(const short8*)((const char*)Bs[cur] + (wc + 16 * j + lm) * 64 + quad * 16);
#pragma unroll
        for (int i = 0; i < 2; ++i)
#pragma unroll
            for (int j = 0; j < 4; ++j)
                acc[i][j] = __builtin_amdgcn_mfma_f32_16x16x32_bf16(af[i], bfv[j], acc[i][j], 0, 0, 0);

        // release: frag reads drained -> safe to re-stage this buffer
        asm volatile("s_waitcnt lgkmcnt(0)\ns_barrier" ::: "memory");
        if (kk + 2 < nk) stage((kk + 2) * 32, cur);
    }

    // C/D layout: col = lane&15, row = quad*4 + reg  [m89-verified]
    const int cr = quad * 4;
#pragma unroll
    for (int i = 0; i < 2; ++i) {
        const int gr = row0 + wr + 16 * i + cr;
#pragma unroll
        for (int j = 0; j < 4; ++j) {
            const int gc = col0 + wc + 16 * j + lm;
            if (MODE == 0) {
#pragma unroll
                for (int rr = 0; rr < 4; ++rr)
                    ((float*)Cv)[(size_t)(gr + rr) * N + gc] = acc[i][j][rr];
            } else if (gc < 2560) {
#pragma unroll
                for (int rr = 0; rr < 4; ++rr)
                    ((u16*)Cv)[(size_t)(gr + rr) * QKD + gc] = f2bf(acc[i][j][rr]);
            } else {
                const int d = gc - 2560;
                ushort4 vv;
                vv.x = f2bf(acc[i][j][0]); vv.y = f2bf(acc[i][j][1]);
                vv.z = f2bf(acc[i][j][2]); vv.w = f2bf(acc[i][j][3]);
                *(ushort4*)(Vt + (size_t)d * S_LEN + gr) = vv;
            }
        }
    }
}

// ---------------------------------------------------------------------------
// MFMA flash attention (R10): Q-tile 128, grid=(16 qtiles, 32 heads), now
// 512 thr / 8 waves — each wave owns ONE 16-row q-group (was 4 waves x two
// groups). Same total MFMA work per block (144/jt) spread over 2x the waves:
// 16 waves/CU (4/SIMD) instead of 8, so the serialized per-jt phase chain
// (QK MFMAs -> exp2/cvt VALU -> P LDS round-trip -> PV MFMAs) of one wave
// overlaps other waves' phases. LDS layouts byte-identical to R7; staging
// re-derived for 512 thr (1 async op per 8KB slab per thread).
// KV-64 double-buffered, prefetch-in-flight: per-thread vm ops are 2 Q +
// 2 per stage_kv -> wait Q at vmcnt(4), acquire at vmcnt(2).
// Scores in log2 domain, fixed cap -16; row sums via ones-fragment MFMA.
// ---------------------------------------------------------------------------
__global__ __launch_bounds__(512)
void attn_mfma(const u16* __restrict__ QK, const u16* __restrict__ Vtg,
               u16* __restrict__ Ctx) {
    // union region: Q staging (2 slabs x 8192B) then P (128 x 144B = 18432B)
    __shared__ __attribute__((aligned(16))) u16 QPs[9216];       // 18432B
    __shared__ __attribute__((aligned(16))) u16 Ks[2][4096];     // 2 x 8KB
    __shared__ __attribute__((aligned(16))) u16 Vts[2][4096];    // 2 x 8KB

    const int t = threadIdx.x;           // 0..511
    const int lane = t & 63;
    const int w = t >> 6;                // 0..7
    const int lm = lane & 15, quad = lane >> 4;
    const int qt = (gridDim.x - 1) - blockIdx.x;   // longest first (LPT)
    const int h = blockIdx.y;
    const int kh = h >> 2;
    const int q0 = qt * 128;
    const int njt = 2 * qt + 2;                    // kv tiles of 64

    const char* Kb = (const char*)(QK + 2048 + kh * HD);
    const char* Vb = (const char*)(Vtg + (size_t)(kh * 64) * S_LEN);

    // staging decomposition for 512 threads x 16B = one 8KB slab per op
    const int sr = (t >> 2) & 63;        // row within 64-row slab
    const int sl = t >> 8;               // slab 0/1 (d-half for K, kv-half for V)
    const int sc = (t & 3) * 16;         // 16B column within 64B row

    // stage Q: thread t stages row t>>2 (0..127) for both d-slabs (2 vm ops).
    // wave w's threads t in [w*64, w*64+64) stage exactly rows w*16..w*16+15
    // -> read-set == staged-set per wave -> per-wave vmcnt wait is sufficient.
    {
        const char* qb = (const char*)(QK + h * HD)
                       + (size_t)(q0 + (t >> 2)) * (QKD * 2) + (t & 3) * 16;
        async_copy16((char*)QPs + t * 16, qb);
        async_copy16((char*)QPs + 8192 + t * 16, qb + 64);
    }

    auto stage_kv = [&](int jt_, int buf) {
        const int j0_ = jt_ * 64;
        async_copy16((char*)Ks + buf * 8192 + t * 16,
                     Kb + (size_t)(j0_ + sr) * (QKD * 2) + sl * 64 + sc);
        async_copy16((char*)Vts + buf * 8192 + t * 16,
                     Vb + (size_t)sr * (S_LEN * 2) + j0_ * 2 + sl * 64 + sc);
    };

    stage_kv(0, 0);
    stage_kv(1, 1);   // njt >= 2 always

    // wait for this wave's Q (2 oldest of 6); KV prefetches stay in flight
    asm volatile("s_waitcnt vmcnt(4)" ::: "memory");

    // one-time Q fragment loads (B-operand: rows = q)
    const int ra = w * 16 + lm;          // this lane's local q row
    const short8 qa0 = *(const short8*)((const char*)QPs +        ra * 64 + quad * 16);
    const short8 qa1 = *(const short8*)((const char*)QPs + 8192 + ra * 64 + quad * 16);
    // drain Q reads before any wave can alias QPs with P writes
    asm volatile("s_waitcnt lgkmcnt(0)" ::: "memory");

    // constant ones A-frag: row m=0 (lanes with lm==0) = 1.0
    short8 onesf;
    {
        const short ob = (lm == 0) ? (short)0x3F80 : (short)0;
#pragma unroll
        for (int j = 0; j < 8; ++j) onesf[j] = ob;
    }

    f32x4 oa[4], la;
#pragma unroll
    for (int dt = 0; dt < 4; ++dt) oa[dt] = (f32x4){0.f, 0.f, 0.f, 0.f};
    la = (f32x4){0.f, 0.f, 0.f, 0.f};

    for (int jt = 0; jt < njt; ++jt) {
        const int cur = jt & 1;
        if (jt + 1 < njt) { asm volatile("s_waitcnt vmcnt(2)\ns_barrier" ::: "memory"); }
        else              { asm volatile("s_waitcnt vmcnt(0)\ns_barrier" ::: "memory"); }

        const char* Kc = (const char*)Ks + cur * 8192;
        const char* Vc = (const char*)Vts + cur * 8192;

        // S^T = K Q^T, log2 domain, cap -16
        f32x4 sa[4];
#pragma unroll
        for (int ct = 0; ct < 4; ++ct)
            sa[ct] = (f32x4){-16.f, -16.f, -16.f, -16.f};
#pragma unroll
        for (int ct = 0; ct < 4; ++ct) {
            short8 kf0 = *(const short8*)(Kc + (ct * 16 + lm) * 64 + quad * 16);
            short8 kf1 = *(const short8*)(Kc + 4096 + (ct * 16 + lm) * 64 + quad * 16);
            sa[ct] = __builtin_amdgcn_mfma_f32_16x16x32_bf16(kf0, qa0, sa[ct], 0, 0, 0);
            sa[ct] = __builtin_amdgcn_mfma_f32_16x16x32_bf16(kf1, qa1, sa[ct], 0, 0, 0);
        }
        // causal mask on the two diagonal-overlapping tiles
        if (jt >= 2 * qt) {
            const int off = (jt - 2 * qt) * 64;
#pragma unroll
            for (int ct = 0; ct < 4; ++ct) {
                const int kvl = off + ct * 16 + quad * 4;
#pragma unroll
                for (int r = 0; r < 4; ++r)
                    if (kvl + r > ra) sa[ct][r] = -1e30f;
            }
        }
        // p = exp2(s); pack 4 kv -> one b64 LDS write per ct
#pragma unroll
        for (int ct = 0; ct < 4; ++ct) {
            ushort4 pka;
            pka.x = f2bf(__builtin_amdgcn_exp2f(sa[ct][0]));
            pka.y = f2bf(__builtin_amdgcn_exp2f(sa[ct][1]));
            pka.z = f2bf(__builtin_amdgcn_exp2f(sa[ct][2]));
            pka.w = f2bf(__builtin_amdgcn_exp2f(sa[ct][3]));
            *(ushort4*)((char*)QPs + ra * 144 + ct * 32 + quad * 8) = pka;
        }
        // P frags (wave-private rows, in-order LDS pipe)
        const short8 pa0 = *(const short8*)((const char*)QPs + ra * 144 +      quad * 16);
        const short8 pa1 = *(const short8*)((const char*)QPs + ra * 144 + 64 + quad * 16);
        // O^T += V^T P^T; l += ones . P
#pragma unroll
        for (int dt = 0; dt < 4; ++dt) {
            short8 vf0 = *(const short8*)(Vc + (dt * 16 + lm) * 64 + quad * 16);
            short8 vf1 = *(const short8*)(Vc + 4096 + (dt * 16 + lm) * 64 + quad * 16);
            oa[dt] = __builtin_amdgcn_mfma_f32_16x16x32_bf16(vf0, pa0, oa[dt], 0, 0, 0);
            oa[dt] = __builtin_amdgcn_mfma_f32_16x16x32_bf16(vf1, pa1, oa[dt], 0, 0, 0);
        }
        la = __builtin_amdgcn_mfma_f32_16x16x32_bf16(onesf, pa0, la, 0, 0, 0);
        la = __builtin_amdgcn_mfma_f32_16x16x32_bf16(onesf, pa1, la, 0, 0, 0);

        // all waves done reading buf[cur] -> safe to prefetch jt+2 into it
        asm volatile("s_waitcnt lgkmcnt(0)\ns_barrier" ::: "memory");
        if (jt + 2 < njt) stage_kv(jt + 2, cur);
    }

    // l for q-row ra lives in lane lm (quad 0), reg 0 -> broadcast
    const float inva = 1.f / __shfl(la[0], lm);
    const int rowa = q0 + ra;
#pragma unroll
    for (int dt = 0; dt < 4; ++dt) {
        ushort4 o;
        o.x = f2bf(oa[dt][0] * inva); o.y = f2bf(oa[dt][1] * inva);
        o.z = f2bf(oa[dt][2] * inva); o.w = f2bf(oa[dt][3] * inva);
        *(ushort4*)(Ctx + (size_t)rowa * HID + h * HD + dt * 16 + quad * 4) = o;
    }
}

// ---------------------------------------------------------------------------
extern "C" void kernel_launch(void* const* d_in, const int* in_sizes, int n_in,
                              void* d_out, int out_size, void* d_ws, size_t ws_size,
                              hipStream_t stream) {
    const float* X   = (const float*)d_in[0];
    const int*   pos = (const int*)d_in[1];
    const float* Wq  = (const float*)d_in[2];
    const float* Wk  = (const float*)d_in[3];
    const float* Wv  = (const float*)d_in[4];
    const float* Wo  = (const float*)d_in[5];
    float* out = (float*)d_out;

    // ws (bf16 elems): Xb 4M | WqkvT 6M | WoT 4M | QK 5M | Vt 1M  ~= 42 MB
    u16* Xb    = (u16*)d_ws;
    u16* WqkvT = Xb + (size_t)4194304;
    u16* WoT   = WqkvT + (size_t)6291456;
    u16* QK    = WoT + (size_t)4194304;
    u16* Vt    = QK + (size_t)S_LEN * QKD;
    u16* Ctxb  = Xb;   // Xb dead after QKV GEMM

    cast_bf16<<<2048, 256, 0, stream>>>(X, Xb, 524288);
    transpose_all<<<dim3(64, 64, 4), 256, 0, stream>>>(Wq, Wk, Wv, Wo, WqkvT, WoT);

    gemm_bt<1><<<dim3(24, 16), 512, 0, stream>>>(Xb, WqkvT, QK, Vt, 2048, 3072, 2048);

    rope_qk<<<10240, 256, 0, stream>>>(QK, pos);

    attn_mfma<<<dim3(16, 32), 512, 0, stream>>>(QK, Vt, Ctxb);

    gemm_bt<0><<<dim3(16, 16), 512, 0, stream>>>(Ctxb, WoT, out, nullptr, 2048, 2048, 2048);
}

// Round 2
// 253.252 us; speedup vs baseline: 1.0141x; 1.0141x over previous
//
#include <hip/hip_runtime.h>
#include <hip/hip_bf16.h>
#include <math.h>

#define S_LEN 2048
#define HID   2048
#define NH    32
#define NKV   8
#define HD    64
#define QKD   2560   // QK buffer row stride: Q[0:2048] | K[2048:2560]
#define LOG2E 1.44269504f
#define L2THETA_32 0.591611505f   // log2(500000)/32

typedef unsigned short u16;
typedef __attribute__((ext_vector_type(8))) short short8;   // 8 bf16 (MFMA A/B frag)
typedef __attribute__((ext_vector_type(4))) float f32x4;    // MFMA C/D frag

__device__ __forceinline__ u16 f2bf(float x) {
    union { __hip_bfloat16 b; u16 u; } c; c.b = __float2bfloat16(x); return c.u;
}
__device__ __forceinline__ float bf2f(u16 u) {
    union { unsigned int i; float f; } c; c.i = ((unsigned int)u) << 16; return c.f;
}
__device__ __forceinline__ void async_copy16(void* lds, const void* g) {
    __builtin_amdgcn_global_load_lds((const __attribute__((address_space(1))) unsigned int*)g,
                                     (__attribute__((address_space(3))) unsigned int*)lds,
                                     16, 0, 0);
}

// ---------------------------------------------------------------------------
__global__ __launch_bounds__(256)
void cast_bf16(const float* __restrict__ in, u16* __restrict__ out, int n8) {
    int i = blockIdx.x * blockDim.x + threadIdx.x;
    if (i >= n8) return;
    const float4* p = (const float4*)(in + (size_t)i * 8);
    float4 a = p[0], b = p[1];
    short8 o;
    o[0] = f2bf(a.x); o[1] = f2bf(a.y); o[2] = f2bf(a.z); o[3] = f2bf(a.w);
    o[4] = f2bf(b.x); o[5] = f2bf(b.y); o[6] = f2bf(b.z); o[7] = f2bf(b.w);
    *(short8*)(out + (size_t)i * 8) = o;
}

// ---------------------------------------------------------------------------
// All four weight transposes in one dispatch. z selects the weight.
// ---------------------------------------------------------------------------
__global__ __launch_bounds__(256)
void transpose_all(const float* __restrict__ Wq, const float* __restrict__ Wk,
                   const float* __restrict__ Wv, const float* __restrict__ Wo,
                   u16* __restrict__ WqkvT, u16* __restrict__ WoT) {
    const float* W; u16* WT; int Nin, xT;
    switch (blockIdx.z) {
        case 0:  W = Wq; WT = WqkvT;                         Nin = 2048; xT = 64; break;
        case 1:  W = Wk; WT = WqkvT + (size_t)2048 * 2048;   Nin = 512;  xT = 16; break;
        case 2:  W = Wv; WT = WqkvT + (size_t)2560 * 2048;   Nin = 512;  xT = 16; break;
        default: W = Wo; WT = WoT;                           Nin = 2048; xT = 64; break;
    }
    if ((int)blockIdx.x >= xT) return;
    __shared__ float tile[32][33];
    const int tx = threadIdx.x & 31, ty = threadIdx.x >> 5;
    const int x = blockIdx.x * 32 + tx;
#pragma unroll
    for (int j = ty; j < 32; j += 8)
        tile[j][tx] = W[(size_t)(blockIdx.y * 32 + j) * Nin + x];
    __syncthreads();
    const int xo = blockIdx.y * 32 + tx;
#pragma unroll
    for (int j = ty; j < 32; j += 8)
        WT[(size_t)(blockIdx.x * 32 + j) * 2048 + xo] = f2bf(tile[tx][j]);
}

// ---------------------------------------------------------------------------
// Standalone RoPE over Q (hh 0..31) and K (hh 32..39). Q gets 0.125*log2e
// folded in (attention works in the log2 domain and calls exp2 directly).
// ---------------------------------------------------------------------------
__global__ __launch_bounds__(256)
void rope_qk(u16* __restrict__ QK, const int* __restrict__ pos) {
    int idx = blockIdx.x * blockDim.x + threadIdx.x;
    int d = idx & 31;
    int hh = (idx >> 5) % 40;
    int s = idx / (32 * 40);
    if (s >= S_LEN) return;
    float p = (float)pos[s];
    float inv_freq = exp2f(-(float)d * L2THETA_32);   // theta^(-d/32)
    float ang = p * inv_freq;
    float c = cosf(ang), sn = sinf(ang);
    float sc = (hh < 32) ? 0.125f * LOG2E : 1.0f;
    u16* b = QK + (size_t)s * QKD + hh * HD;
    float x0 = bf2f(b[d]), x1 = bf2f(b[d + 32]);
    b[d]      = f2bf((x0 * c - x1 * sn) * sc);
    b[d + 32] = f2bf((x1 * c + x0 * sn) * sc);
}

// ---------------------------------------------------------------------------
// bf16 GEMM (R9): 512 threads / 8 waves, 128x128 tile, BK=32, double-buffered
// LDS with prefetch-in-flight (vmcnt(2) acquire — 2 vm ops per stage at 512
// thr). Wave micro-tile 32x64 (2x4 accs, 8 MFMAs/iter).
// MODE 0: fp32 C (stride N).
// MODE 1: QKV epilogue — cols <2560 -> bf16 QK (stride QKD); cols >=2560 ->
// V written TRANSPOSED to Vt[d][s].
// ---------------------------------------------------------------------------
template<int MODE>
__global__ __launch_bounds__(512)
void gemm_bt(const u16* __restrict__ A, const u16* __restrict__ Bt,
             void* __restrict__ Cv, u16* __restrict__ Vt, int M, int N, int K) {
    __shared__ __attribute__((aligned(16))) u16 As[2][4096];   // 2 x 8KB
    __shared__ __attribute__((aligned(16))) u16 Bs[2][4096];   // 2 x 8KB
    const int t = threadIdx.x;           // 0..511
    const int lane = t & 63;
    const int w = t >> 6;                // 0..7
    const int lm = lane & 15, quad = lane >> 4;
    const int row0 = blockIdx.y * 128, col0 = blockIdx.x * 128;
    const int wr = (w >> 1) * 32, wc = (w & 1) * 64;   // wave = 32 rows x 64 cols

    f32x4 acc[2][4];
#pragma unroll
    for (int i = 0; i < 2; ++i)
#pragma unroll
        for (int j = 0; j < 4; ++j) acc[i][j] = (f32x4){0.f, 0.f, 0.f, 0.f};

    const size_t strideB = (size_t)K * 2;
    const char* Ab = (const char*)(A + (size_t)row0 * K);
    const char* Bb = (const char*)(Bt + (size_t)col0 * K);

    // stage one 128x32 k-tile pair: 2 vm ops per thread (A, B); 512x16B = 8KB
    auto stage = [&](int k0, int buf) {
        const int f = t * 16;
        const int r = f >> 6, cb = f & 63;
        async_copy16((char*)As[buf] + f, Ab + (size_t)r * strideB + k0 * 2 + cb);
        async_copy16((char*)Bs[buf] + f, Bb + (size_t)r * strideB + k0 * 2 + cb);
    };

    const int nk = K >> 5;
    stage(0, 0);
    if (nk > 1) stage(32, 1);

    for (int kk = 0; kk < nk; ++kk) {
        const int cur = kk & 1;
        // acquire: tile kk resident; tile kk+1 (2 ops) may stay in flight
        if (kk + 1 < nk) { asm volatile("s_waitcnt vmcnt(2)\ns_barrier" ::: "memory"); }
        else             { asm volatile("s_waitcnt vmcnt(0)\ns_barrier" ::: "memory"); }

        short8 af[2], bfv[4];
#pragma unroll
        for (int i = 0; i < 2; ++i)
            af[i] = *(const short8*)((const char*)As[cur] + (wr + 16 * i + lm) * 64 + quad * 16);
#pragma unroll
        for (int j = 0; j < 4; ++j)
            bfv[j] = *(const short8*)((const char*)Bs[cur] + (wc + 16 * j + lm) * 64 + quad * 16);
#pragma unroll
        for (int i = 0; i < 2; ++i)
#pragma unroll
            for (int j = 0; j < 4; ++j)
                acc[i][j] = __builtin_amdgcn_mfma_f32_16x16x32_bf16(af[i], bfv[j], acc[i][j], 0, 0, 0);

        // release: frag reads drained -> safe to re-stage this buffer
        asm volatile("s_waitcnt lgkmcnt(0)\ns_barrier" ::: "memory");
        if (kk + 2 < nk) stage((kk + 2) * 32, cur);
    }

    // C/D layout: col = lane&15, row = quad*4 + reg  [m89-verified]
    const int cr = quad * 4;
#pragma unroll
    for (int i = 0; i < 2; ++i) {
        const int gr = row0 + wr + 16 * i + cr;
#pragma unroll
        for (int j = 0; j < 4; ++j) {
            const int gc = col0 + wc + 16 * j + lm;
            if (MODE == 0) {
#pragma unroll
                for (int rr = 0; rr < 4; ++rr)
                    ((float*)Cv)[(size_t)(gr + rr) * N + gc] = acc[i][j][rr];
            } else if (gc < 2560) {
#pragma unroll
                for (int rr = 0; rr < 4; ++rr)
                    ((u16*)Cv)[(size_t)(gr + rr) * QKD + gc] = f2bf(acc[i][j][rr]);
            } else {
                const int d = gc - 2560;
                ushort4 vv;
                vv.x = f2bf(acc[i][j][0]); vv.y = f2bf(acc[i][j][1]);
                vv.z = f2bf(acc[i][j][2]); vv.w = f2bf(acc[i][j][3]);
                *(ushort4*)(Vt + (size_t)d * S_LEN + gr) = vv;
            }
        }
    }
}

// ---------------------------------------------------------------------------
// MFMA flash attention (R11): back to 4 waves / 256 thr (R7 structure — each
// wave owns TWO 16-row q-groups, halving per-block LDS frag traffic vs R10's
// 8 waves), PLUS conflict-free XOR-swizzled LDS layouts. Diagnosis: kernel is
// LDS-read-bound; the old 64B-row layouts gave 8-way bank conflicts on every
// ds_read_b128 (quad's 16 lanes -> 2 bank-groups). New unified layouts:
//   K:  [64 kv][128B d]   V: [64 d][128B kv]   Q/P: [128 q][128B]
// each row = 8 x 16B chunks, stored swizzled chunk' = chunk ^ (row&7) via
// PRE-SWIZZLED GLOBAL SOURCE (LDS dest stays linear for global_load_lds,
// rule 21) and read with the same XOR. All frag reads have row&7 == lm&7, so
// the read offset is a single constant fswz = (quad^(lm&7))<<4; the second
// d/kv-half is fswz^64. After swizzle each quad's 16 lanes spread across all
// 8 bank-groups (2-way = free, m136). P reuses the Q region (wave-private
// rows, in-order LDS pipe). vmcnt discipline unchanged (4 ops/stage).
// ---------------------------------------------------------------------------
__global__ __launch_bounds__(256)
void attn_mfma(const u16* __restrict__ QK, const u16* __restrict__ Vtg,
               u16* __restrict__ Ctx) {
    __shared__ __attribute__((aligned(16))) u16 QPs[8192];       // 16KB Q then P
    __shared__ __attribute__((aligned(16))) u16 Ks[2][4096];     // 2 x 8KB [64][128B]
    __shared__ __attribute__((aligned(16))) u16 Vts[2][4096];    // 2 x 8KB [64][128B]

    const int t = threadIdx.x;           // 0..255
    const int lane = t & 63;
    const int w = t >> 6;                // 0..3
    const int lm = lane & 15, quad = lane >> 4;
    const int qt = (gridDim.x - 1) - blockIdx.x;   // longest first (LPT)
    const int h = blockIdx.y;
    const int kh = h >> 2;
    const int q0 = qt * 128;
    const int njt = 2 * qt + 2;                    // kv tiles of 64

    const char* Kb = (const char*)(QK + 2048 + kh * HD);
    const char* Vb = (const char*)(Vtg + (size_t)(kh * 64) * S_LEN);

    // staging: thread t covers LDS rows srow and srow+32, chunk t&7;
    // source chunk pre-swizzled: chunk' = (t&7) ^ (row&7), row&7 == srow&7
    const int srow = t >> 3;                         // 0..31
    const int scswz = ((t & 7) ^ (srow & 7)) * 16;

    // stage Q: wave w stages its own rows [w*32, w*32+32) (4 vm ops;
    // read-set == staged-set per wave -> per-wave vmcnt wait is sufficient)
    {
        const char* qb = (const char*)(QK + h * HD);
        const int qrow = w * 32 + (lane >> 3);       // + k2*8; row&7 = lane>>3
        const int qcs = ((lane & 7) ^ (lane >> 3)) * 16;
#pragma unroll
        for (int k2 = 0; k2 < 4; ++k2)
            async_copy16((char*)QPs + w * 4096 + k2 * 1024 + lane * 16,
                         qb + (size_t)(q0 + qrow + k2 * 8) * (QKD * 2) + qcs);
    }

    auto stage_kv = [&](int jt_, int buf) {
        const int j0_ = jt_ * 64;
        char* kdst = (char*)Ks + buf * 8192 + t * 16;
        char* vdst = (char*)Vts + buf * 8192 + t * 16;
        async_copy16(kdst,        Kb + (size_t)(j0_ + srow)      * (QKD * 2) + scswz);
        async_copy16(kdst + 4096, Kb + (size_t)(j0_ + 32 + srow) * (QKD * 2) + scswz);
        async_copy16(vdst,        Vb + (size_t)srow        * (S_LEN * 2) + j0_ * 2 + scswz);
        async_copy16(vdst + 4096, Vb + (size_t)(32 + srow) * (S_LEN * 2) + j0_ * 2 + scswz);
    };

    stage_kv(0, 0);
    stage_kv(1, 1);   // njt >= 2 always

    // wait for this wave's Q (4 oldest of 12); KV prefetches stay in flight
    asm volatile("s_waitcnt vmcnt(8)" ::: "memory");

    // one-time Q fragment loads (B-operand: rows = q); swizzled read offset
    const int ra = w * 32 + lm, rb = ra + 16;        // ra&7 == rb&7 == lm&7
    const int fswz = ((quad ^ (lm & 7)) << 4);
    const short8 qa0 = *(const short8*)((const char*)QPs + ra * 128 + fswz);
    const short8 qa1 = *(const short8*)((const char*)QPs + ra * 128 + (fswz ^ 64));
    const short8 qb0 = *(const short8*)((const char*)QPs + rb * 128 + fswz);
    const short8 qb1 = *(const short8*)((const char*)QPs + rb * 128 + (fswz ^ 64));
    // drain Q reads before P writes alias the region (wave-private rows)
    asm volatile("s_waitcnt lgkmcnt(0)" ::: "memory");

    // constant ones A-frag: row m=0 (lanes with lm==0) = 1.0
    short8 onesf;
    {
        const short ob = (lm == 0) ? (short)0x3F80 : (short)0;
#pragma unroll
        for (int j = 0; j < 8; ++j) onesf[j] = ob;
    }

    f32x4 oa[4], ob_[4], la, lb;
#pragma unroll
    for (int dt = 0; dt < 4; ++dt) { oa[dt] = (f32x4){0.f,0.f,0.f,0.f}; ob_[dt] = (f32x4){0.f,0.f,0.f,0.f}; }
    la = (f32x4){0.f, 0.f, 0.f, 0.f};
    lb = (f32x4){0.f, 0.f, 0.f, 0.f};

    for (int jt = 0; jt < njt; ++jt) {
        const int cur = jt & 1;
        if (jt + 1 < njt) { asm volatile("s_waitcnt vmcnt(4)\ns_barrier" ::: "memory"); }
        else              { asm volatile("s_waitcnt vmcnt(0)\ns_barrier" ::: "memory"); }

        const char* Kc = (const char*)Ks + cur * 8192;
        const char* Vc = (const char*)Vts + cur * 8192;

        // S^T = K Q^T for both q-groups (shared K frags), log2 domain, cap -16
        f32x4 sa[4], sb[4];
#pragma unroll
        for (int ct = 0; ct < 4; ++ct) {
            sa[ct] = (f32x4){-16.f, -16.f, -16.f, -16.f};
            sb[ct] = (f32x4){-16.f, -16.f, -16.f, -16.f};
        }
#pragma unroll
        for (int ct = 0; ct < 4; ++ct) {
            const char* kr = Kc + (ct * 16 + lm) * 128;
            short8 kf0 = *(const short8*)(kr + fswz);
            short8 kf1 = *(const short8*)(kr + (fswz ^ 64));
            sa[ct] = __builtin_amdgcn_mfma_f32_16x16x32_bf16(kf0, qa0, sa[ct], 0, 0, 0);
            sa[ct] = __builtin_amdgcn_mfma_f32_16x16x32_bf16(kf1, qa1, sa[ct], 0, 0, 0);
            sb[ct] = __builtin_amdgcn_mfma_f32_16x16x32_bf16(kf0, qb0, sb[ct], 0, 0, 0);
            sb[ct] = __builtin_amdgcn_mfma_f32_16x16x32_bf16(kf1, qb1, sb[ct], 0, 0, 0);
        }
        // causal mask on the two diagonal-overlapping tiles
        if (jt >= 2 * qt) {
            const int off = (jt - 2 * qt) * 64;
#pragma unroll
            for (int ct = 0; ct < 4; ++ct) {
                const int kvl = off + ct * 16 + quad * 4;
#pragma unroll
                for (int r = 0; r < 4; ++r) {
                    if (kvl + r > ra) sa[ct][r] = -1e30f;
                    if (kvl + r > rb) sb[ct][r] = -1e30f;
                }
            }
        }
        // p = exp2(s); pack 4 kv -> one b64 swizzled LDS write per ct per group
#pragma unroll
        for (int ct = 0; ct < 4; ++ct) {
            ushort4 pka, pkb;
            pka.x = f2bf(__builtin_amdgcn_exp2f(sa[ct][0]));
            pka.y = f2bf(__builtin_amdgcn_exp2f(sa[ct][1]));
            pka.z = f2bf(__builtin_amdgcn_exp2f(sa[ct][2]));
            pka.w = f2bf(__builtin_amdgcn_exp2f(sa[ct][3]));
            pkb.x = f2bf(__builtin_amdgcn_exp2f(sb[ct][0]));
            pkb.y = f2bf(__builtin_amdgcn_exp2f(sb[ct][1]));
            pkb.z = f2bf(__builtin_amdgcn_exp2f(sb[ct][2]));
            pkb.w = f2bf(__builtin_amdgcn_exp2f(sb[ct][3]));
            const int pc = (((2 * ct + (quad >> 1)) ^ (lm & 7)) << 4) + ((quad & 1) << 3);
            *(ushort4*)((char*)QPs + ra * 128 + pc) = pka;
            *(ushort4*)((char*)QPs + rb * 128 + pc) = pkb;
        }
        // P frags (wave-private rows, in-order LDS pipe); same fswz pattern
        const short8 pa0 = *(const short8*)((const char*)QPs + ra * 128 + fswz);
        const short8 pa1 = *(const short8*)((const char*)QPs + ra * 128 + (fswz ^ 64));
        const short8 pb0 = *(const short8*)((const char*)QPs + rb * 128 + fswz);
        const short8 pb1 = *(const short8*)((const char*)QPs + rb * 128 + (fswz ^ 64));
        // O^T += V^T P^T for both groups (shared V frags); l += ones . P
#pragma unroll
        for (int dt = 0; dt < 4; ++dt) {
            const char* vr = Vc + (dt * 16 + lm) * 128;
            short8 vf0 = *(const short8*)(vr + fswz);
            short8 vf1 = *(const short8*)(vr + (fswz ^ 64));
            oa[dt]  = __builtin_amdgcn_mfma_f32_16x16x32_bf16(vf0, pa0, oa[dt], 0, 0, 0);
            oa[dt]  = __builtin_amdgcn_mfma_f32_16x16x32_bf16(vf1, pa1, oa[dt], 0, 0, 0);
            ob_[dt] = __builtin_amdgcn_mfma_f32_16x16x32_bf16(vf0, pb0, ob_[dt], 0, 0, 0);
            ob_[dt] = __builtin_amdgcn_mfma_f32_16x16x32_bf16(vf1, pb1, ob_[dt], 0, 0, 0);
        }
        la = __builtin_amdgcn_mfma_f32_16x16x32_bf16(onesf, pa0, la, 0, 0, 0);
        la = __builtin_amdgcn_mfma_f32_16x16x32_bf16(onesf, pa1, la, 0, 0, 0);
        lb = __builtin_amdgcn_mfma_f32_16x16x32_bf16(onesf, pb0, lb, 0, 0, 0);
        lb = __builtin_amdgcn_mfma_f32_16x16x32_bf16(onesf, pb1, lb, 0, 0, 0);

        // all waves done reading buf[cur] -> safe to prefetch jt+2 into it
        asm volatile("s_waitcnt lgkmcnt(0)\ns_barrier" ::: "memory");
        if (jt + 2 < njt) stage_kv(jt + 2, cur);
    }

    // l for q-row ra/rb lives in lane lm (quad 0), reg 0 -> broadcast
    const float inva = 1.f / __shfl(la[0], lm);
    const float invb = 1.f / __shfl(lb[0], lm);
    const int rowa = q0 + ra, rowb = q0 + rb;
#pragma unroll
    for (int dt = 0; dt < 4; ++dt) {
        ushort4 o;
        o.x = f2bf(oa[dt][0] * inva); o.y = f2bf(oa[dt][1] * inva);
        o.z = f2bf(oa[dt][2] * inva); o.w = f2bf(oa[dt][3] * inva);
        *(ushort4*)(Ctx + (size_t)rowa * HID + h * HD + dt * 16 + quad * 4) = o;
        ushort4 p;
        p.x = f2bf(ob_[dt][0] * invb); p.y = f2bf(ob_[dt][1] * invb);
        p.z = f2bf(ob_[dt][2] * invb); p.w = f2bf(ob_[dt][3] * invb);
        *(ushort4*)(Ctx + (size_t)rowb * HID + h * HD + dt * 16 + quad * 4) = p;
    }
}

// ---------------------------------------------------------------------------
extern "C" void kernel_launch(void* const* d_in, const int* in_sizes, int n_in,
                              void* d_out, int out_size, void* d_ws, size_t ws_size,
                              hipStream_t stream) {
    const float* X   = (const float*)d_in[0];
    const int*   pos = (const int*)d_in[1];
    const float* Wq  = (const float*)d_in[2];
    const float* Wk  = (const float*)d_in[3];
    const float* Wv  = (const float*)d_in[4];
    const float* Wo  = (const float*)d_in[5];
    float* out = (float*)d_out;

    // ws (bf16 elems): Xb 4M | WqkvT 6M | WoT 4M | QK 5M | Vt 1M  ~= 42 MB
    u16* Xb    = (u16*)d_ws;
    u16* WqkvT = Xb + (size_t)4194304;
    u16* WoT   = WqkvT + (size_t)6291456;
    u16* QK    = WoT + (size_t)4194304;
    u16* Vt    = QK + (size_t)S_LEN * QKD;
    u16* Ctxb  = Xb;   // Xb dead after QKV GEMM

    cast_bf16<<<2048, 256, 0, stream>>>(X, Xb, 524288);
    transpose_all<<<dim3(64, 64, 4), 256, 0, stream>>>(Wq, Wk, Wv, Wo, WqkvT, WoT);

    gemm_bt<1><<<dim3(24, 16), 512, 0, stream>>>(Xb, WqkvT, QK, Vt, 2048, 3072, 2048);

    rope_qk<<<10240, 256, 0, stream>>>(QK, pos);

    attn_mfma<<<dim3(16, 32), 256, 0, stream>>>(QK, Vt, Ctxb);

    gemm_bt<0><<<dim3(16, 16), 512, 0, stream>>>(Ctxb, WoT, out, nullptr, 2048, 2048, 2048);
}

// Round 3
// 250.999 us; speedup vs baseline: 1.0232x; 1.0090x over previous
//
#include <hip/hip_runtime.h>
#include <hip/hip_bf16.h>
#include <math.h>

#define S_LEN 2048
#define HID   2048
#define NH    32
#define NKV   8
#define HD    64
#define QKD   2560   // QK buffer row stride: Q[0:2048] | K[2048:2560]
#define LOG2E 1.44269504f
#define L2THETA_32 0.591611505f   // log2(500000)/32

typedef unsigned short u16;
typedef __attribute__((ext_vector_type(8))) short short8;   // 8 bf16 (MFMA A/B frag)
typedef __attribute__((ext_vector_type(4))) float f32x4;    // MFMA C/D frag

__device__ __forceinline__ u16 f2bf(float x) {
    union { __hip_bfloat16 b; u16 u; } c; c.b = __float2bfloat16(x); return c.u;
}
__device__ __forceinline__ float bf2f(u16 u) {
    union { unsigned int i; float f; } c; c.i = ((unsigned int)u) << 16; return c.f;
}
__device__ __forceinline__ void async_copy16(void* lds, const void* g) {
    __builtin_amdgcn_global_load_lds((const __attribute__((address_space(1))) unsigned int*)g,
                                     (__attribute__((address_space(3))) unsigned int*)lds,
                                     16, 0, 0);
}

// ---------------------------------------------------------------------------
__global__ __launch_bounds__(256)
void cast_bf16(const float* __restrict__ in, u16* __restrict__ out, int n8) {
    int i = blockIdx.x * blockDim.x + threadIdx.x;
    if (i >= n8) return;
    const float4* p = (const float4*)(in + (size_t)i * 8);
    float4 a = p[0], b = p[1];
    short8 o;
    o[0] = f2bf(a.x); o[1] = f2bf(a.y); o[2] = f2bf(a.z); o[3] = f2bf(a.w);
    o[4] = f2bf(b.x); o[5] = f2bf(b.y); o[6] = f2bf(b.z); o[7] = f2bf(b.w);
    *(short8*)(out + (size_t)i * 8) = o;
}

// ---------------------------------------------------------------------------
// All four weight transposes in one dispatch. z selects the weight.
// ---------------------------------------------------------------------------
__global__ __launch_bounds__(256)
void transpose_all(const float* __restrict__ Wq, const float* __restrict__ Wk,
                   const float* __restrict__ Wv, const float* __restrict__ Wo,
                   u16* __restrict__ WqkvT, u16* __restrict__ WoT) {
    const float* W; u16* WT; int Nin, xT;
    switch (blockIdx.z) {
        case 0:  W = Wq; WT = WqkvT;                         Nin = 2048; xT = 64; break;
        case 1:  W = Wk; WT = WqkvT + (size_t)2048 * 2048;   Nin = 512;  xT = 16; break;
        case 2:  W = Wv; WT = WqkvT + (size_t)2560 * 2048;   Nin = 512;  xT = 16; break;
        default: W = Wo; WT = WoT;                           Nin = 2048; xT = 64; break;
    }
    if ((int)blockIdx.x >= xT) return;
    __shared__ float tile[32][33];
    const int tx = threadIdx.x & 31, ty = threadIdx.x >> 5;
    const int x = blockIdx.x * 32 + tx;
#pragma unroll
    for (int j = ty; j < 32; j += 8)
        tile[j][tx] = W[(size_t)(blockIdx.y * 32 + j) * Nin + x];
    __syncthreads();
    const int xo = blockIdx.y * 32 + tx;
#pragma unroll
    for (int j = ty; j < 32; j += 8)
        WT[(size_t)(blockIdx.x * 32 + j) * 2048 + xo] = f2bf(tile[tx][j]);
}

// ---------------------------------------------------------------------------
// Standalone RoPE over Q (hh 0..31) and K (hh 32..39). Q gets 0.125*log2e
// folded in (attention works in the log2 domain and calls exp2 directly).
// ---------------------------------------------------------------------------
__global__ __launch_bounds__(256)
void rope_qk(u16* __restrict__ QK, const int* __restrict__ pos) {
    int idx = blockIdx.x * blockDim.x + threadIdx.x;
    int d = idx & 31;
    int hh = (idx >> 5) % 40;
    int s = idx / (32 * 40);
    if (s >= S_LEN) return;
    float p = (float)pos[s];
    float inv_freq = exp2f(-(float)d * L2THETA_32);   // theta^(-d/32)
    float ang = p * inv_freq;
    float c = cosf(ang), sn = sinf(ang);
    float sc = (hh < 32) ? 0.125f * LOG2E : 1.0f;
    u16* b = QK + (size_t)s * QKD + hh * HD;
    float x0 = bf2f(b[d]), x1 = bf2f(b[d + 32]);
    b[d]      = f2bf((x0 * c - x1 * sn) * sc);
    b[d + 32] = f2bf((x1 * c + x0 * sn) * sc);
}

// ---------------------------------------------------------------------------
// bf16 GEMM (R9): 512 threads / 8 waves, 128x128 tile, BK=32, double-buffered
// LDS with prefetch-in-flight (vmcnt(2) acquire — 2 vm ops per stage at 512
// thr). Wave micro-tile 32x64 (2x4 accs, 8 MFMAs/iter).
// MODE 0: fp32 C (stride N).
// MODE 1: QKV epilogue — cols <2560 -> bf16 QK (stride QKD); cols >=2560 ->
// V written TRANSPOSED to Vt[d][s].
// ---------------------------------------------------------------------------
template<int MODE>
__global__ __launch_bounds__(512)
void gemm_bt(const u16* __restrict__ A, const u16* __restrict__ Bt,
             void* __restrict__ Cv, u16* __restrict__ Vt, int M, int N, int K) {
    __shared__ __attribute__((aligned(16))) u16 As[2][4096];   // 2 x 8KB
    __shared__ __attribute__((aligned(16))) u16 Bs[2][4096];   // 2 x 8KB
    const int t = threadIdx.x;           // 0..511
    const int lane = t & 63;
    const int w = t >> 6;                // 0..7
    const int lm = lane & 15, quad = lane >> 4;
    const int row0 = blockIdx.y * 128, col0 = blockIdx.x * 128;
    const int wr = (w >> 1) * 32, wc = (w & 1) * 64;   // wave = 32 rows x 64 cols

    f32x4 acc[2][4];
#pragma unroll
    for (int i = 0; i < 2; ++i)
#pragma unroll
        for (int j = 0; j < 4; ++j) acc[i][j] = (f32x4){0.f, 0.f, 0.f, 0.f};

    const size_t strideB = (size_t)K * 2;
    const char* Ab = (const char*)(A + (size_t)row0 * K);
    const char* Bb = (const char*)(Bt + (size_t)col0 * K);

    // stage one 128x32 k-tile pair: 2 vm ops per thread (A, B); 512x16B = 8KB
    auto stage = [&](int k0, int buf) {
        const int f = t * 16;
        const int r = f >> 6, cb = f & 63;
        async_copy16((char*)As[buf] + f, Ab + (size_t)r * strideB + k0 * 2 + cb);
        async_copy16((char*)Bs[buf] + f, Bb + (size_t)r * strideB + k0 * 2 + cb);
    };

    const int nk = K >> 5;
    stage(0, 0);
    if (nk > 1) stage(32, 1);

    for (int kk = 0; kk < nk; ++kk) {
        const int cur = kk & 1;
        // acquire: tile kk resident; tile kk+1 (2 ops) may stay in flight
        if (kk + 1 < nk) { asm volatile("s_waitcnt vmcnt(2)\ns_barrier" ::: "memory"); }
        else             { asm volatile("s_waitcnt vmcnt(0)\ns_barrier" ::: "memory"); }

        short8 af[2], bfv[4];
#pragma unroll
        for (int i = 0; i < 2; ++i)
            af[i] = *(const short8*)((const char*)As[cur] + (wr + 16 * i + lm) * 64 + quad * 16);
#pragma unroll
        for (int j = 0; j < 4; ++j)
            bfv[j] = *(const short8*)((const char*)Bs[cur] + (wc + 16 * j + lm) * 64 + quad * 16);
#pragma unroll
        for (int i = 0; i < 2; ++i)
#pragma unroll
            for (int j = 0; j < 4; ++j)
                acc[i][j] = __builtin_amdgcn_mfma_f32_16x16x32_bf16(af[i], bfv[j], acc[i][j], 0, 0, 0);

        // release: frag reads drained -> safe to re-stage this buffer
        asm volatile("s_waitcnt lgkmcnt(0)\ns_barrier" ::: "memory");
        if (kk + 2 < nk) stage((kk + 2) * 32, cur);
    }

    // C/D layout: col = lane&15, row = quad*4 + reg  [m89-verified]
    const int cr = quad * 4;
#pragma unroll
    for (int i = 0; i < 2; ++i) {
        const int gr = row0 + wr + 16 * i + cr;
#pragma unroll
        for (int j = 0; j < 4; ++j) {
            const int gc = col0 + wc + 16 * j + lm;
            if (MODE == 0) {
#pragma unroll
                for (int rr = 0; rr < 4; ++rr)
                    ((float*)Cv)[(size_t)(gr + rr) * N + gc] = acc[i][j][rr];
            } else if (gc < 2560) {
#pragma unroll
                for (int rr = 0; rr < 4; ++rr)
                    ((u16*)Cv)[(size_t)(gr + rr) * QKD + gc] = f2bf(acc[i][j][rr]);
            } else {
                const int d = gc - 2560;
                ushort4 vv;
                vv.x = f2bf(acc[i][j][0]); vv.y = f2bf(acc[i][j][1]);
                vv.z = f2bf(acc[i][j][2]); vv.w = f2bf(acc[i][j][3]);
                *(ushort4*)(Vt + (size_t)d * S_LEN + gr) = vv;
            }
        }
    }
}

// ---------------------------------------------------------------------------
// MFMA flash attention (R12): Q-tile 64, grid=(32 qtiles, 32 heads) = 1024
// blocks. Diagnosis from R11: latency-bound — no pipe above ~30%, chain-
// limited with only ~2 blocks/CU (grid-limited, not resource-limited). Finer
// grid supplies ~4 blocks/CU (LDS 40KB). Each of 4 waves owns ONE 16-row
// q-group (R11 minus the whole b-group); njt = qt+1 kv-tiles of 64. Swizzled
// conflict-free layouts identical to R11:
//   K: [64 kv][128B d]  V: [64 d][128B kv]  Q/P union: [64 q][128B]
// chunk' = chunk ^ (row&7) via pre-swizzled global source (LDS dest linear,
// rule 21); frag reads at fswz = (quad^(lm&7))<<4, second half fswz^64.
// vmcnt: Q(2 ops) + 4/stage -> Q-wait vmcnt(8) (vmcnt(4) if njt==1),
// acquire vmcnt(4)/(0). Scores log2-domain, fixed cap -16; row sums via
// ones-fragment MFMA.
// ---------------------------------------------------------------------------
__global__ __launch_bounds__(256)
void attn_mfma(const u16* __restrict__ QK, const u16* __restrict__ Vtg,
               u16* __restrict__ Ctx) {
    __shared__ __attribute__((aligned(16))) u16 QPs[4096];       // 8KB Q then P
    __shared__ __attribute__((aligned(16))) u16 Ks[2][4096];     // 2 x 8KB [64][128B]
    __shared__ __attribute__((aligned(16))) u16 Vts[2][4096];    // 2 x 8KB [64][128B]

    const int t = threadIdx.x;           // 0..255
    const int lane = t & 63;
    const int w = t >> 6;                // 0..3
    const int lm = lane & 15, quad = lane >> 4;
    const int qt = (gridDim.x - 1) - blockIdx.x;   // longest first (LPT)
    const int h = blockIdx.y;
    const int kh = h >> 2;
    const int q0 = qt * 64;
    const int njt = qt + 1;                        // kv tiles of 64

    const char* Kb = (const char*)(QK + 2048 + kh * HD);
    const char* Vb = (const char*)(Vtg + (size_t)(kh * 64) * S_LEN);

    // staging: thread t covers LDS rows srow and srow+32, chunk t&7;
    // source chunk pre-swizzled: chunk' = (t&7) ^ (row&7), row&7 == srow&7
    const int srow = t >> 3;                         // 0..31
    const int scswz = ((t & 7) ^ (srow & 7)) * 16;

    // stage Q: wave w stages its own rows [w*16, w*16+16) (2 vm ops;
    // read-set == staged-set per wave -> per-wave vmcnt wait is sufficient)
    {
        const char* qb = (const char*)(QK + h * HD);
        const int qrow = w * 16 + (lane >> 3);       // + k2*8; row&7 = lane>>3
        const int qcs = ((lane & 7) ^ (lane >> 3)) * 16;
#pragma unroll
        for (int k2 = 0; k2 < 2; ++k2)
            async_copy16((char*)QPs + w * 2048 + k2 * 1024 + lane * 16,
                         qb + (size_t)(q0 + qrow + k2 * 8) * (QKD * 2) + qcs);
    }

    auto stage_kv = [&](int jt_, int buf) {
        const int j0_ = jt_ * 64;
        char* kdst = (char*)Ks + buf * 8192 + t * 16;
        char* vdst = (char*)Vts + buf * 8192 + t * 16;
        async_copy16(kdst,        Kb + (size_t)(j0_ + srow)      * (QKD * 2) + scswz);
        async_copy16(kdst + 4096, Kb + (size_t)(j0_ + 32 + srow) * (QKD * 2) + scswz);
        async_copy16(vdst,        Vb + (size_t)srow        * (S_LEN * 2) + j0_ * 2 + scswz);
        async_copy16(vdst + 4096, Vb + (size_t)(32 + srow) * (S_LEN * 2) + j0_ * 2 + scswz);
    };

    stage_kv(0, 0);
    if (njt > 1) {
        stage_kv(1, 1);
        // wait for this wave's Q (2 oldest of 10); KV prefetches in flight
        asm volatile("s_waitcnt vmcnt(8)" ::: "memory");
    } else {
        // only Q(2) + kv0(4) outstanding -> Q done at vmcnt(4)
        asm volatile("s_waitcnt vmcnt(4)" ::: "memory");
    }

    // one-time Q fragment loads (B-operand: rows = q); swizzled read offset
    const int ra = w * 16 + lm;                      // ra&7 == lm&7
    const int fswz = ((quad ^ (lm & 7)) << 4);
    const short8 qa0 = *(const short8*)((const char*)QPs + ra * 128 + fswz);
    const short8 qa1 = *(const short8*)((const char*)QPs + ra * 128 + (fswz ^ 64));
    // drain Q reads before P writes alias the region (wave-private rows)
    asm volatile("s_waitcnt lgkmcnt(0)" ::: "memory");

    // constant ones A-frag: row m=0 (lanes with lm==0) = 1.0
    short8 onesf;
    {
        const short ob = (lm == 0) ? (short)0x3F80 : (short)0;
#pragma unroll
        for (int j = 0; j < 8; ++j) onesf[j] = ob;
    }

    f32x4 oa[4], la;
#pragma unroll
    for (int dt = 0; dt < 4; ++dt) oa[dt] = (f32x4){0.f, 0.f, 0.f, 0.f};
    la = (f32x4){0.f, 0.f, 0.f, 0.f};

    for (int jt = 0; jt < njt; ++jt) {
        const int cur = jt & 1;
        if (jt + 1 < njt) { asm volatile("s_waitcnt vmcnt(4)\ns_barrier" ::: "memory"); }
        else              { asm volatile("s_waitcnt vmcnt(0)\ns_barrier" ::: "memory"); }

        const char* Kc = (const char*)Ks + cur * 8192;
        const char* Vc = (const char*)Vts + cur * 8192;

        // S^T = K Q^T, log2 domain, cap -16
        f32x4 sa[4];
#pragma unroll
        for (int ct = 0; ct < 4; ++ct)
            sa[ct] = (f32x4){-16.f, -16.f, -16.f, -16.f};
#pragma unroll
        for (int ct = 0; ct < 4; ++ct) {
            const char* kr = Kc + (ct * 16 + lm) * 128;
            short8 kf0 = *(const short8*)(kr + fswz);
            short8 kf1 = *(const short8*)(kr + (fswz ^ 64));
            sa[ct] = __builtin_amdgcn_mfma_f32_16x16x32_bf16(kf0, qa0, sa[ct], 0, 0, 0);
            sa[ct] = __builtin_amdgcn_mfma_f32_16x16x32_bf16(kf1, qa1, sa[ct], 0, 0, 0);
        }
        // causal mask: only the diagonal tile (jt == qt)
        if (jt == qt) {
#pragma unroll
            for (int ct = 0; ct < 4; ++ct) {
                const int kvl = ct * 16 + quad * 4;
#pragma unroll
                for (int r = 0; r < 4; ++r)
                    if (kvl + r > ra) sa[ct][r] = -1e30f;
            }
        }
        // p = exp2(s); pack 4 kv -> one b64 swizzled LDS write per ct
#pragma unroll
        for (int ct = 0; ct < 4; ++ct) {
            ushort4 pka;
            pka.x = f2bf(__builtin_amdgcn_exp2f(sa[ct][0]));
            pka.y = f2bf(__builtin_amdgcn_exp2f(sa[ct][1]));
            pka.z = f2bf(__builtin_amdgcn_exp2f(sa[ct][2]));
            pka.w = f2bf(__builtin_amdgcn_exp2f(sa[ct][3]));
            const int pc = (((2 * ct + (quad >> 1)) ^ (lm & 7)) << 4) + ((quad & 1) << 3);
            *(ushort4*)((char*)QPs + ra * 128 + pc) = pka;
        }
        // P frags (wave-private rows, in-order LDS pipe); same fswz pattern
        const short8 pa0 = *(const short8*)((const char*)QPs + ra * 128 + fswz);
        const short8 pa1 = *(const short8*)((const char*)QPs + ra * 128 + (fswz ^ 64));
        // O^T += V^T P^T; l += ones . P
#pragma unroll
        for (int dt = 0; dt < 4; ++dt) {
            const char* vr = Vc + (dt * 16 + lm) * 128;
            short8 vf0 = *(const short8*)(vr + fswz);
            short8 vf1 = *(const short8*)(vr + (fswz ^ 64));
            oa[dt] = __builtin_amdgcn_mfma_f32_16x16x32_bf16(vf0, pa0, oa[dt], 0, 0, 0);
            oa[dt] = __builtin_amdgcn_mfma_f32_16x16x32_bf16(vf1, pa1, oa[dt], 0, 0, 0);
        }
        la = __builtin_amdgcn_mfma_f32_16x16x32_bf16(onesf, pa0, la, 0, 0, 0);
        la = __builtin_amdgcn_mfma_f32_16x16x32_bf16(onesf, pa1, la, 0, 0, 0);

        // all waves done reading buf[cur] -> safe to prefetch jt+2 into it
        asm volatile("s_waitcnt lgkmcnt(0)\ns_barrier" ::: "memory");
        if (jt + 2 < njt) stage_kv(jt + 2, cur);
    }

    // l for q-row ra lives in lane lm (quad 0), reg 0 -> broadcast
    const float inva = 1.f / __shfl(la[0], lm);
    const int rowa = q0 + ra;
#pragma unroll
    for (int dt = 0; dt < 4; ++dt) {
        ushort4 o;
        o.x = f2bf(oa[dt][0] * inva); o.y = f2bf(oa[dt][1] * inva);
        o.z = f2bf(oa[dt][2] * inva); o.w = f2bf(oa[dt][3] * inva);
        *(ushort4*)(Ctx + (size_t)rowa * HID + h * HD + dt * 16 + quad * 4) = o;
    }
}

// ---------------------------------------------------------------------------
extern "C" void kernel_launch(void* const* d_in, const int* in_sizes, int n_in,
                              void* d_out, int out_size, void* d_ws, size_t ws_size,
                              hipStream_t stream) {
    const float* X   = (const float*)d_in[0];
    const int*   pos = (const int*)d_in[1];
    const float* Wq  = (const float*)d_in[2];
    const float* Wk  = (const float*)d_in[3];
    const float* Wv  = (const float*)d_in[4];
    const float* Wo  = (const float*)d_in[5];
    float* out = (float*)d_out;

    // ws (bf16 elems): Xb 4M | WqkvT 6M | WoT 4M | QK 5M | Vt 1M  ~= 42 MB
    u16* Xb    = (u16*)d_ws;
    u16* WqkvT = Xb + (size_t)4194304;
    u16* WoT   = WqkvT + (size_t)6291456;
    u16* QK    = WoT + (size_t)4194304;
    u16* Vt    = QK + (size_t)S_LEN * QKD;
    u16* Ctxb  = Xb;   // Xb dead after QKV GEMM

    cast_bf16<<<2048, 256, 0, stream>>>(X, Xb, 524288);
    transpose_all<<<dim3(64, 64, 4), 256, 0, stream>>>(Wq, Wk, Wv, Wo, WqkvT, WoT);

    gemm_bt<1><<<dim3(24, 16), 512, 0, stream>>>(Xb, WqkvT, QK, Vt, 2048, 3072, 2048);

    rope_qk<<<10240, 256, 0, stream>>>(QK, pos);

    attn_mfma<<<dim3(32, 32), 256, 0, stream>>>(QK, Vt, Ctxb);

    gemm_bt<0><<<dim3(16, 16), 512, 0, stream>>>(Ctxb, WoT, out, nullptr, 2048, 2048, 2048);
}

// Round 4
// 230.228 us; speedup vs baseline: 1.1155x; 1.0902x over previous
//
#include <hip/hip_runtime.h>
#include <hip/hip_bf16.h>
#include <math.h>

#define S_LEN 2048
#define HID   2048
#define NH    32
#define NKV   8
#define HD    64
#define QKD   2560   // QK buffer row stride: Q[0:2048] | K[2048:2560]
#define LOG2E 1.44269504f
#define L2THETA_32 0.591611505f   // log2(500000)/32

typedef unsigned short u16;
typedef __attribute__((ext_vector_type(8))) short short8;   // 8 bf16 (MFMA A/B frag)
typedef __attribute__((ext_vector_type(4))) float f32x4;    // MFMA C/D frag

__device__ __forceinline__ u16 f2bf(float x) {
    union { __hip_bfloat16 b; u16 u; } c; c.b = __float2bfloat16(x); return c.u;
}
__device__ __forceinline__ float bf2f(u16 u) {
    union { unsigned int i; float f; } c; c.i = ((unsigned int)u) << 16; return c.f;
}
__device__ __forceinline__ void async_copy16(void* lds, const void* g) {
    __builtin_amdgcn_global_load_lds((const __attribute__((address_space(1))) unsigned int*)g,
                                     (__attribute__((address_space(3))) unsigned int*)lds,
                                     16, 0, 0);
}

// ---------------------------------------------------------------------------
__global__ __launch_bounds__(256)
void cast_bf16(const float* __restrict__ in, u16* __restrict__ out, int n8) {
    int i = blockIdx.x * blockDim.x + threadIdx.x;
    if (i >= n8) return;
    const float4* p = (const float4*)(in + (size_t)i * 8);
    float4 a = p[0], b = p[1];
    short8 o;
    o[0] = f2bf(a.x); o[1] = f2bf(a.y); o[2] = f2bf(a.z); o[3] = f2bf(a.w);
    o[4] = f2bf(b.x); o[5] = f2bf(b.y); o[6] = f2bf(b.z); o[7] = f2bf(b.w);
    *(short8*)(out + (size_t)i * 8) = o;
}

// ---------------------------------------------------------------------------
// All four weight transposes in one dispatch. z selects the weight.
// ---------------------------------------------------------------------------
__global__ __launch_bounds__(256)
void transpose_all(const float* __restrict__ Wq, const float* __restrict__ Wk,
                   const float* __restrict__ Wv, const float* __restrict__ Wo,
                   u16* __restrict__ WqkvT, u16* __restrict__ WoT) {
    const float* W; u16* WT; int Nin, xT;
    switch (blockIdx.z) {
        case 0:  W = Wq; WT = WqkvT;                         Nin = 2048; xT = 64; break;
        case 1:  W = Wk; WT = WqkvT + (size_t)2048 * 2048;   Nin = 512;  xT = 16; break;
        case 2:  W = Wv; WT = WqkvT + (size_t)2560 * 2048;   Nin = 512;  xT = 16; break;
        default: W = Wo; WT = WoT;                           Nin = 2048; xT = 64; break;
    }
    if ((int)blockIdx.x >= xT) return;
    __shared__ float tile[32][33];
    const int tx = threadIdx.x & 31, ty = threadIdx.x >> 5;
    const int x = blockIdx.x * 32 + tx;
#pragma unroll
    for (int j = ty; j < 32; j += 8)
        tile[j][tx] = W[(size_t)(blockIdx.y * 32 + j) * Nin + x];
    __syncthreads();
    const int xo = blockIdx.y * 32 + tx;
#pragma unroll
    for (int j = ty; j < 32; j += 8)
        WT[(size_t)(blockIdx.x * 32 + j) * 2048 + xo] = f2bf(tile[tx][j]);
}

// ---------------------------------------------------------------------------
// Standalone RoPE over Q (hh 0..31) and K (hh 32..39). Q gets 0.125*log2e
// folded in (attention works in the log2 domain and calls exp2 directly).
// ---------------------------------------------------------------------------
__global__ __launch_bounds__(256)
void rope_qk(u16* __restrict__ QK, const int* __restrict__ pos) {
    int idx = blockIdx.x * blockDim.x + threadIdx.x;
    int d = idx & 31;
    int hh = (idx >> 5) % 40;
    int s = idx / (32 * 40);
    if (s >= S_LEN) return;
    float p = (float)pos[s];
    float inv_freq = exp2f(-(float)d * L2THETA_32);   // theta^(-d/32)
    float ang = p * inv_freq;
    float c = cosf(ang), sn = sinf(ang);
    float sc = (hh < 32) ? 0.125f * LOG2E : 1.0f;
    u16* b = QK + (size_t)s * QKD + hh * HD;
    float x0 = bf2f(b[d]), x1 = bf2f(b[d + 32]);
    b[d]      = f2bf((x0 * c - x1 * sn) * sc);
    b[d + 32] = f2bf((x1 * c + x0 * sn) * sc);
}

// ---------------------------------------------------------------------------
// bf16 GEMM (R13): 256 threads / 4 waves, 128x64 tile, BK=64, double-buffered
// LDS, conflict-free swizzled 128B rows (same chunk^(row&7) scheme as attn,
// pre-swizzled global source + fswz frag reads). Retiled from 128x128 so the
// grid divides 256 CUs exactly: gemm<1> 48x16=768 blocks (3.0/CU), gemm<0>
// 32x16=512 (2.0/CU) — removes the 2-vs-1 block imbalance of the 384/256
// grids and gives 2-3 independent blocks per CU to overlap barrier stalls.
// Staging: 6 uniform ops/thread/stage (4 A + 2 B), acquire vmcnt(6);
// 16 MFMAs/wave/stage; 32 stages at K=2048. LDS 48KB -> 3 blocks/CU.
// Wave w owns rows [w*32, w*32+32) x all 64 cols (2x4 accs).
// MODE 0: fp32 C (stride N).
// MODE 1: QKV epilogue — cols <2560 -> bf16 QK (stride QKD); cols >=2560 ->
// V written TRANSPOSED to Vt[d][s].
// ---------------------------------------------------------------------------
template<int MODE>
__global__ __launch_bounds__(256)
void gemm_bt(const u16* __restrict__ A, const u16* __restrict__ Bt,
             void* __restrict__ Cv, u16* __restrict__ Vt, int M, int N, int K) {
    __shared__ __attribute__((aligned(16))) u16 As[2][8192];   // 2 x 16KB [128][128B]
    __shared__ __attribute__((aligned(16))) u16 Bs[2][4096];   // 2 x 8KB  [64][128B]
    const int t = threadIdx.x;           // 0..255
    const int lane = t & 63;
    const int w = t >> 6;                // 0..3
    const int lm = lane & 15, quad = lane >> 4;
    const int row0 = blockIdx.y * 128, col0 = blockIdx.x * 64;
    const int wr = w * 32;               // wave = 32 rows x 64 cols

    f32x4 acc[2][4];
#pragma unroll
    for (int i = 0; i < 2; ++i)
#pragma unroll
        for (int j = 0; j < 4; ++j) acc[i][j] = (f32x4){0.f, 0.f, 0.f, 0.f};

    const size_t strideB = (size_t)K * 2;
    const char* Ab = (const char*)(A + (size_t)row0 * K);
    const char* Bb = (const char*)(Bt + (size_t)col0 * K);

    // staging: thread t covers LDS rows {i*32 + t>>3}, chunk t&7 (8 x 16B
    // chunks per 128B row); source chunk pre-swizzled: (t&7) ^ (row&7)
    const int srow = t >> 3;                         // 0..31
    const int scswz = ((t & 7) ^ (srow & 7)) * 16;

    // one k-stage = 64 k: A 128x128B (4 ops) + B 64x128B (2 ops), uniform
    auto stage = [&](int ks, int buf) {
        const int k0b = ks * 128;        // byte offset along k
        char* ad = (char*)As[buf] + t * 16;
        char* bd = (char*)Bs[buf] + t * 16;
#pragma unroll
        for (int i = 0; i < 4; ++i)
            async_copy16(ad + i * 4096, Ab + (size_t)(i * 32 + srow) * strideB + k0b + scswz);
#pragma unroll
        for (int i = 0; i < 2; ++i)
            async_copy16(bd + i * 4096, Bb + (size_t)(i * 32 + srow) * strideB + k0b + scswz);
    };

    const int nk = K >> 6;
    stage(0, 0);
    if (nk > 1) stage(1, 1);

    const int fswz = (quad ^ (lm & 7)) << 4;

    for (int kk = 0; kk < nk; ++kk) {
        const int cur = kk & 1;
        // acquire: stage kk resident; stage kk+1 (6 ops) may stay in flight
        if (kk + 1 < nk) { asm volatile("s_waitcnt vmcnt(6)\ns_barrier" ::: "memory"); }
        else             { asm volatile("s_waitcnt vmcnt(0)\ns_barrier" ::: "memory"); }

        short8 af[2][2], bfv[4][2];
#pragma unroll
        for (int i = 0; i < 2; ++i) {
            const char* ar = (const char*)As[cur] + (wr + 16 * i + lm) * 128;
            af[i][0] = *(const short8*)(ar + fswz);
            af[i][1] = *(const short8*)(ar + (fswz ^ 64));
        }
#pragma unroll
        for (int j = 0; j < 4; ++j) {
            const char* br = (const char*)Bs[cur] + (16 * j + lm) * 128;
            bfv[j][0] = *(const short8*)(br + fswz);
            bfv[j][1] = *(const short8*)(br + (fswz ^ 64));
        }
#pragma unroll
        for (int i = 0; i < 2; ++i)
#pragma unroll
            for (int j = 0; j < 4; ++j) {
                acc[i][j] = __builtin_amdgcn_mfma_f32_16x16x32_bf16(af[i][0], bfv[j][0], acc[i][j], 0, 0, 0);
                acc[i][j] = __builtin_amdgcn_mfma_f32_16x16x32_bf16(af[i][1], bfv[j][1], acc[i][j], 0, 0, 0);
            }

        // release: frag reads drained -> safe to re-stage this buffer
        asm volatile("s_waitcnt lgkmcnt(0)\ns_barrier" ::: "memory");
        if (kk + 2 < nk) stage(kk + 2, cur);
    }

    // C/D layout: col = lane&15, row = quad*4 + reg  [m89-verified]
    const int cr = quad * 4;
#pragma unroll
    for (int i = 0; i < 2; ++i) {
        const int gr = row0 + wr + 16 * i + cr;
#pragma unroll
        for (int j = 0; j < 4; ++j) {
            const int gc = col0 + 16 * j + lm;
            if (MODE == 0) {
#pragma unroll
                for (int rr = 0; rr < 4; ++rr)
                    ((float*)Cv)[(size_t)(gr + rr) * N + gc] = acc[i][j][rr];
            } else if (gc < 2560) {
#pragma unroll
                for (int rr = 0; rr < 4; ++rr)
                    ((u16*)Cv)[(size_t)(gr + rr) * QKD + gc] = f2bf(acc[i][j][rr]);
            } else {
                const int d = gc - 2560;
                ushort4 vv;
                vv.x = f2bf(acc[i][j][0]); vv.y = f2bf(acc[i][j][1]);
                vv.z = f2bf(acc[i][j][2]); vv.w = f2bf(acc[i][j][3]);
                *(ushort4*)(Vt + (size_t)d * S_LEN + gr) = vv;
            }
        }
    }
}

// ---------------------------------------------------------------------------
// MFMA flash attention (R12, unchanged): Q-tile 64, grid=(32 qtiles, 32
// heads) = 1024 blocks, 4 waves x one 16-row q-group, njt = qt+1 kv-tiles.
// Swizzled conflict-free layouts:
//   K: [64 kv][128B d]  V: [64 d][128B kv]  Q/P union: [64 q][128B]
// chunk' = chunk ^ (row&7) via pre-swizzled global source (LDS dest linear,
// rule 21); frag reads at fswz = (quad^(lm&7))<<4, second half fswz^64.
// vmcnt: Q(2 ops) + 4/stage -> Q-wait vmcnt(8) (vmcnt(4) if njt==1),
// acquire vmcnt(4)/(0). Scores log2-domain, fixed cap -16; row sums via
// ones-fragment MFMA.
// ---------------------------------------------------------------------------
__global__ __launch_bounds__(256)
void attn_mfma(const u16* __restrict__ QK, const u16* __restrict__ Vtg,
               u16* __restrict__ Ctx) {
    __shared__ __attribute__((aligned(16))) u16 QPs[4096];       // 8KB Q then P
    __shared__ __attribute__((aligned(16))) u16 Ks[2][4096];     // 2 x 8KB [64][128B]
    __shared__ __attribute__((aligned(16))) u16 Vts[2][4096];    // 2 x 8KB [64][128B]

    const int t = threadIdx.x;           // 0..255
    const int lane = t & 63;
    const int w = t >> 6;                // 0..3
    const int lm = lane & 15, quad = lane >> 4;
    const int qt = (gridDim.x - 1) - blockIdx.x;   // longest first (LPT)
    const int h = blockIdx.y;
    const int kh = h >> 2;
    const int q0 = qt * 64;
    const int njt = qt + 1;                        // kv tiles of 64

    const char* Kb = (const char*)(QK + 2048 + kh * HD);
    const char* Vb = (const char*)(Vtg + (size_t)(kh * 64) * S_LEN);

    // staging: thread t covers LDS rows srow and srow+32, chunk t&7;
    // source chunk pre-swizzled: chunk' = (t&7) ^ (row&7), row&7 == srow&7
    const int srow = t >> 3;                         // 0..31
    const int scswz = ((t & 7) ^ (srow & 7)) * 16;

    // stage Q: wave w stages its own rows [w*16, w*16+16) (2 vm ops;
    // read-set == staged-set per wave -> per-wave vmcnt wait is sufficient)
    {
        const char* qb = (const char*)(QK + h * HD);
        const int qrow = w * 16 + (lane >> 3);       // + k2*8; row&7 = lane>>3
        const int qcs = ((lane & 7) ^ (lane >> 3)) * 16;
#pragma unroll
        for (int k2 = 0; k2 < 2; ++k2)
            async_copy16((char*)QPs + w * 2048 + k2 * 1024 + lane * 16,
                         qb + (size_t)(q0 + qrow + k2 * 8) * (QKD * 2) + qcs);
    }

    auto stage_kv = [&](int jt_, int buf) {
        const int j0_ = jt_ * 64;
        char* kdst = (char*)Ks + buf * 8192 + t * 16;
        char* vdst = (char*)Vts + buf * 8192 + t * 16;
        async_copy16(kdst,        Kb + (size_t)(j0_ + srow)      * (QKD * 2) + scswz);
        async_copy16(kdst + 4096, Kb + (size_t)(j0_ + 32 + srow) * (QKD * 2) + scswz);
        async_copy16(vdst,        Vb + (size_t)srow        * (S_LEN * 2) + j0_ * 2 + scswz);
        async_copy16(vdst + 4096, Vb + (size_t)(32 + srow) * (S_LEN * 2) + j0_ * 2 + scswz);
    };

    stage_kv(0, 0);
    if (njt > 1) {
        stage_kv(1, 1);
        // wait for this wave's Q (2 oldest of 10); KV prefetches in flight
        asm volatile("s_waitcnt vmcnt(8)" ::: "memory");
    } else {
        // only Q(2) + kv0(4) outstanding -> Q done at vmcnt(4)
        asm volatile("s_waitcnt vmcnt(4)" ::: "memory");
    }

    // one-time Q fragment loads (B-operand: rows = q); swizzled read offset
    const int ra = w * 16 + lm;                      // ra&7 == lm&7
    const int fswz = ((quad ^ (lm & 7)) << 4);
    const short8 qa0 = *(const short8*)((const char*)QPs + ra * 128 + fswz);
    const short8 qa1 = *(const short8*)((const char*)QPs + ra * 128 + (fswz ^ 64));
    // drain Q reads before P writes alias the region (wave-private rows)
    asm volatile("s_waitcnt lgkmcnt(0)" ::: "memory");

    // constant ones A-frag: row m=0 (lanes with lm==0) = 1.0
    short8 onesf;
    {
        const short ob = (lm == 0) ? (short)0x3F80 : (short)0;
#pragma unroll
        for (int j = 0; j < 8; ++j) onesf[j] = ob;
    }

    f32x4 oa[4], la;
#pragma unroll
    for (int dt = 0; dt < 4; ++dt) oa[dt] = (f32x4){0.f, 0.f, 0.f, 0.f};
    la = (f32x4){0.f, 0.f, 0.f, 0.f};

    for (int jt = 0; jt < njt; ++jt) {
        const int cur = jt & 1;
        if (jt + 1 < njt) { asm volatile("s_waitcnt vmcnt(4)\ns_barrier" ::: "memory"); }
        else              { asm volatile("s_waitcnt vmcnt(0)\ns_barrier" ::: "memory"); }

        const char* Kc = (const char*)Ks + cur * 8192;
        const char* Vc = (const char*)Vts + cur * 8192;

        // S^T = K Q^T, log2 domain, cap -16
        f32x4 sa[4];
#pragma unroll
        for (int ct = 0; ct < 4; ++ct)
            sa[ct] = (f32x4){-16.f, -16.f, -16.f, -16.f};
#pragma unroll
        for (int ct = 0; ct < 4; ++ct) {
            const char* kr = Kc + (ct * 16 + lm) * 128;
            short8 kf0 = *(const short8*)(kr + fswz);
            short8 kf1 = *(const short8*)(kr + (fswz ^ 64));
            sa[ct] = __builtin_amdgcn_mfma_f32_16x16x32_bf16(kf0, qa0, sa[ct], 0, 0, 0);
            sa[ct] = __builtin_amdgcn_mfma_f32_16x16x32_bf16(kf1, qa1, sa[ct], 0, 0, 0);
        }
        // causal mask: only the diagonal tile (jt == qt)
        if (jt == qt) {
#pragma unroll
            for (int ct = 0; ct < 4; ++ct) {
                const int kvl = ct * 16 + quad * 4;
#pragma unroll
                for (int r = 0; r < 4; ++r)
                    if (kvl + r > ra) sa[ct][r] = -1e30f;
            }
        }
        // p = exp2(s); pack 4 kv -> one b64 swizzled LDS write per ct
#pragma unroll
        for (int ct = 0; ct < 4; ++ct) {
            ushort4 pka;
            pka.x = f2bf(__builtin_amdgcn_exp2f(sa[ct][0]));
            pka.y = f2bf(__builtin_amdgcn_exp2f(sa[ct][1]));
            pka.z = f2bf(__builtin_amdgcn_exp2f(sa[ct][2]));
            pka.w = f2bf(__builtin_amdgcn_exp2f(sa[ct][3]));
            const int pc = (((2 * ct + (quad >> 1)) ^ (lm & 7)) << 4) + ((quad & 1) << 3);
            *(ushort4*)((char*)QPs + ra * 128 + pc) = pka;
        }
        // P frags (wave-private rows, in-order LDS pipe); same fswz pattern
        const short8 pa0 = *(const short8*)((const char*)QPs + ra * 128 + fswz);
        const short8 pa1 = *(const short8*)((const char*)QPs + ra * 128 + (fswz ^ 64));
        // O^T += V^T P^T; l += ones . P
#pragma unroll
        for (int dt = 0; dt < 4; ++dt) {
            const char* vr = Vc + (dt * 16 + lm) * 128;
            short8 vf0 = *(const short8*)(vr + fswz);
            short8 vf1 = *(const short8*)(vr + (fswz ^ 64));
            oa[dt] = __builtin_amdgcn_mfma_f32_16x16x32_bf16(vf0, pa0, oa[dt], 0, 0, 0);
            oa[dt] = __builtin_amdgcn_mfma_f32_16x16x32_bf16(vf1, pa1, oa[dt], 0, 0, 0);
        }
        la = __builtin_amdgcn_mfma_f32_16x16x32_bf16(onesf, pa0, la, 0, 0, 0);
        la = __builtin_amdgcn_mfma_f32_16x16x32_bf16(onesf, pa1, la, 0, 0, 0);

        // all waves done reading buf[cur] -> safe to prefetch jt+2 into it
        asm volatile("s_waitcnt lgkmcnt(0)\ns_barrier" ::: "memory");
        if (jt + 2 < njt) stage_kv(jt + 2, cur);
    }

    // l for q-row ra lives in lane lm (quad 0), reg 0 -> broadcast
    const float inva = 1.f / __shfl(la[0], lm);
    const int rowa = q0 + ra;
#pragma unroll
    for (int dt = 0; dt < 4; ++dt) {
        ushort4 o;
        o.x = f2bf(oa[dt][0] * inva); o.y = f2bf(oa[dt][1] * inva);
        o.z = f2bf(oa[dt][2] * inva); o.w = f2bf(oa[dt][3] * inva);
        *(ushort4*)(Ctx + (size_t)rowa * HID + h * HD + dt * 16 + quad * 4) = o;
    }
}

// ---------------------------------------------------------------------------
extern "C" void kernel_launch(void* const* d_in, const int* in_sizes, int n_in,
                              void* d_out, int out_size, void* d_ws, size_t ws_size,
                              hipStream_t stream) {
    const float* X   = (const float*)d_in[0];
    const int*   pos = (const int*)d_in[1];
    const float* Wq  = (const float*)d_in[2];
    const float* Wk  = (const float*)d_in[3];
    const float* Wv  = (const float*)d_in[4];
    const float* Wo  = (const float*)d_in[5];
    float* out = (float*)d_out;

    // ws (bf16 elems): Xb 4M | WqkvT 6M | WoT 4M | QK 5M | Vt 1M  ~= 42 MB
    u16* Xb    = (u16*)d_ws;
    u16* WqkvT = Xb + (size_t)4194304;
    u16* WoT   = WqkvT + (size_t)6291456;
    u16* QK    = WoT + (size_t)4194304;
    u16* Vt    = QK + (size_t)S_LEN * QKD;
    u16* Ctxb  = Xb;   // Xb dead after QKV GEMM

    cast_bf16<<<2048, 256, 0, stream>>>(X, Xb, 524288);
    transpose_all<<<dim3(64, 64, 4), 256, 0, stream>>>(Wq, Wk, Wv, Wo, WqkvT, WoT);

    gemm_bt<1><<<dim3(48, 16), 256, 0, stream>>>(Xb, WqkvT, QK, Vt, 2048, 3072, 2048);

    rope_qk<<<10240, 256, 0, stream>>>(QK, pos);

    attn_mfma<<<dim3(32, 32), 256, 0, stream>>>(QK, Vt, Ctxb);

    gemm_bt<0><<<dim3(32, 16), 256, 0, stream>>>(Ctxb, WoT, out, nullptr, 2048, 2048, 2048);
}

// Round 6
// 218.901 us; speedup vs baseline: 1.1732x; 1.0517x over previous
//
#include <hip/hip_runtime.h>
#include <hip/hip_bf16.h>
#include <math.h>

#define S_LEN 2048
#define HID   2048
#define NH    32
#define NKV   8
#define HD    64
#define QKD   2560   // QK buffer row stride: Q[0:2048] | K[2048:2560]
#define LOG2E 1.44269504f
#define L2THETA_32 0.591611505f   // log2(500000)/32

typedef unsigned short u16;
typedef __attribute__((ext_vector_type(8))) short short8;   // 8 bf16 (MFMA A/B frag)
typedef __attribute__((ext_vector_type(4))) float f32x4;    // MFMA C/D frag

__device__ __forceinline__ u16 f2bf(float x) {
    union { __hip_bfloat16 b; u16 u; } c; c.b = __float2bfloat16(x); return c.u;
}
__device__ __forceinline__ float bf2f(u16 u) {
    union { unsigned int i; float f; } c; c.i = ((unsigned int)u) << 16; return c.f;
}
__device__ __forceinline__ void async_copy16(void* lds, const void* g) {
    __builtin_amdgcn_global_load_lds((const __attribute__((address_space(1))) unsigned int*)g,
                                     (__attribute__((address_space(3))) unsigned int*)lds,
                                     16, 0, 0);
}

// ---------------------------------------------------------------------------
// prep (R14): cast_bf16 + all four weight transposes in ONE dispatch.
// z 0..3 selects the weight transpose; z==4 is the X fp32->bf16 cast.
// Merging removes one inter-dispatch gap and overlaps cast under transpose.
// ---------------------------------------------------------------------------
__global__ __launch_bounds__(256)
void prep(const float* __restrict__ X, u16* __restrict__ Xb,
          const float* __restrict__ Wq, const float* __restrict__ Wk,
          const float* __restrict__ Wv, const float* __restrict__ Wo,
          u16* __restrict__ WqkvT, u16* __restrict__ WoT) {
    if (blockIdx.z == 4) {
        // cast: 4.19M floats, 8 per thread; first 2048 of 4096 block slots
        const int i = (blockIdx.y * 64 + (int)blockIdx.x) * 256 + threadIdx.x;
        if (i >= 524288) return;
        const float4* p = (const float4*)(X + (size_t)i * 8);
        float4 a = p[0], b = p[1];
        short8 o;
        o[0] = f2bf(a.x); o[1] = f2bf(a.y); o[2] = f2bf(a.z); o[3] = f2bf(a.w);
        o[4] = f2bf(b.x); o[5] = f2bf(b.y); o[6] = f2bf(b.z); o[7] = f2bf(b.w);
        *(short8*)(Xb + (size_t)i * 8) = o;
        return;
    }
    const float* W; u16* WT; int Nin, xT;
    switch (blockIdx.z) {
        case 0:  W = Wq; WT = WqkvT;                         Nin = 2048; xT = 64; break;
        case 1:  W = Wk; WT = WqkvT + (size_t)2048 * 2048;   Nin = 512;  xT = 16; break;
        case 2:  W = Wv; WT = WqkvT + (size_t)2560 * 2048;   Nin = 512;  xT = 16; break;
        default: W = Wo; WT = WoT;                           Nin = 2048; xT = 64; break;
    }
    if ((int)blockIdx.x >= xT) return;
    __shared__ float tile[32][33];
    const int tx = threadIdx.x & 31, ty = threadIdx.x >> 5;
    const int x = blockIdx.x * 32 + tx;
#pragma unroll
    for (int j = ty; j < 32; j += 8)
        tile[j][tx] = W[(size_t)(blockIdx.y * 32 + j) * Nin + x];
    __syncthreads();
    const int xo = blockIdx.y * 32 + tx;
#pragma unroll
    for (int j = ty; j < 32; j += 8)
        WT[(size_t)(blockIdx.x * 32 + j) * 2048 + xo] = f2bf(tile[tx][j]);
}

// ---------------------------------------------------------------------------
// bf16 GEMM (R14): 256 threads / 4 waves, 128x64 tile, BK=64, double-buffered
// LDS, conflict-free swizzled 128B rows (chunk^(row&7), pre-swizzled global
// source + fswz frag reads). Grids divide 256 CUs exactly: gemm<1> 48x16=768
// (3.0/CU), gemm<0> 32x16=512 (2.0/CU). Staging 6 uniform ops/thread/stage,
// acquire vmcnt(6); 16 MFMAs/wave/stage; LDS 48KB -> 3 blocks/CU.
// MODE 0: fp32 C (stride N).
// MODE 1: QKV epilogue with FUSED RoPE — each block's 64-col tile is exactly
// one head; the RoPE pair (d, d+32) sits in frags (j, j+2) of the same lane/
// row, so rotation needs no cross-lane traffic. Applied to the fp32 acc
// before the bf16 round (old flow rounded first — this is strictly closer to
// the fp32 reference). Q cols get 0.125*LOG2E folded in (attention works in
// the log2 domain). cols >= 2560 -> V written TRANSPOSED to Vt[d][s].
// Replaces the standalone rope_qk dispatch + a 21 MB QK round trip.
// ---------------------------------------------------------------------------
template<int MODE>
__global__ __launch_bounds__(256)
void gemm_bt(const u16* __restrict__ A, const u16* __restrict__ Bt,
             void* __restrict__ Cv, u16* __restrict__ Vt,
             const int* __restrict__ pos, int M, int N, int K) {
    __shared__ __attribute__((aligned(16))) u16 As[2][8192];   // 2 x 16KB [128][128B]
    __shared__ __attribute__((aligned(16))) u16 Bs[2][4096];   // 2 x 8KB  [64][128B]
    const int t = threadIdx.x;           // 0..255
    const int lane = t & 63;
    const int w = t >> 6;                // 0..3
    const int lm = lane & 15, quad = lane >> 4;
    const int row0 = blockIdx.y * 128, col0 = blockIdx.x * 64;
    const int wr = w * 32;               // wave = 32 rows x 64 cols

    f32x4 acc[2][4];
#pragma unroll
    for (int i = 0; i < 2; ++i)
#pragma unroll
        for (int j = 0; j < 4; ++j) acc[i][j] = (f32x4){0.f, 0.f, 0.f, 0.f};

    const size_t strideB = (size_t)K * 2;
    const char* Ab = (const char*)(A + (size_t)row0 * K);
    const char* Bb = (const char*)(Bt + (size_t)col0 * K);

    // staging: thread t covers LDS rows {i*32 + t>>3}, chunk t&7 (8 x 16B
    // chunks per 128B row); source chunk pre-swizzled: (t&7) ^ (row&7)
    const int srow = t >> 3;                         // 0..31
    const int scswz = ((t & 7) ^ (srow & 7)) * 16;

    // one k-stage = 64 k: A 128x128B (4 ops) + B 64x128B (2 ops), uniform
    auto stage = [&](int ks, int buf) {
        const int k0b = ks * 128;        // byte offset along k
        char* ad = (char*)As[buf] + t * 16;
        char* bd = (char*)Bs[buf] + t * 16;
#pragma unroll
        for (int i = 0; i < 4; ++i)
            async_copy16(ad + i * 4096, Ab + (size_t)(i * 32 + srow) * strideB + k0b + scswz);
#pragma unroll
        for (int i = 0; i < 2; ++i)
            async_copy16(bd + i * 4096, Bb + (size_t)(i * 32 + srow) * strideB + k0b + scswz);
    };

    const int nk = K >> 6;
    stage(0, 0);
    if (nk > 1) stage(1, 1);

    const int fswz = (quad ^ (lm & 7)) << 4;

    for (int kk = 0; kk < nk; ++kk) {
        const int cur = kk & 1;
        // acquire: stage kk resident; stage kk+1 (6 ops) may stay in flight
        if (kk + 1 < nk) { asm volatile("s_waitcnt vmcnt(6)\ns_barrier" ::: "memory"); }
        else             { asm volatile("s_waitcnt vmcnt(0)\ns_barrier" ::: "memory"); }

        short8 af[2][2], bfv[4][2];
#pragma unroll
        for (int i = 0; i < 2; ++i) {
            const char* ar = (const char*)As[cur] + (wr + 16 * i + lm) * 128;
            af[i][0] = *(const short8*)(ar + fswz);
            af[i][1] = *(const short8*)(ar + (fswz ^ 64));
        }
#pragma unroll
        for (int j = 0; j < 4; ++j) {
            const char* br = (const char*)Bs[cur] + (16 * j + lm) * 128;
            bfv[j][0] = *(const short8*)(br + fswz);
            bfv[j][1] = *(const short8*)(br + (fswz ^ 64));
        }
#pragma unroll
        for (int i = 0; i < 2; ++i)
#pragma unroll
            for (int j = 0; j < 4; ++j) {
                acc[i][j] = __builtin_amdgcn_mfma_f32_16x16x32_bf16(af[i][0], bfv[j][0], acc[i][j], 0, 0, 0);
                acc[i][j] = __builtin_amdgcn_mfma_f32_16x16x32_bf16(af[i][1], bfv[j][1], acc[i][j], 0, 0, 0);
            }

        // release: frag reads drained -> safe to re-stage this buffer
        asm volatile("s_waitcnt lgkmcnt(0)\ns_barrier" ::: "memory");
        if (kk + 2 < nk) stage(kk + 2, cur);
    }

    // C/D layout: col = lane&15, row = quad*4 + reg  [m89-verified]
    const int cr = quad * 4;
    if (MODE == 0) {
#pragma unroll
        for (int i = 0; i < 2; ++i) {
            const int gr = row0 + wr + 16 * i + cr;
#pragma unroll
            for (int j = 0; j < 4; ++j) {
                const int gc = col0 + 16 * j + lm;
#pragma unroll
                for (int rr = 0; rr < 4; ++rr)
                    ((float*)Cv)[(size_t)(gr + rr) * N + gc] = acc[i][j][rr];
            }
        }
    } else if (col0 >= 2560) {
        // V written transposed to Vt[d][s]
#pragma unroll
        for (int i = 0; i < 2; ++i) {
            const int gr = row0 + wr + 16 * i + cr;
#pragma unroll
            for (int j = 0; j < 4; ++j) {
                const int d = col0 + 16 * j + lm - 2560;
                ushort4 vv;
                vv.x = f2bf(acc[i][j][0]); vv.y = f2bf(acc[i][j][1]);
                vv.z = f2bf(acc[i][j][2]); vv.w = f2bf(acc[i][j][3]);
                *(ushort4*)(Vt + (size_t)d * S_LEN + gr) = vv;
            }
        }
    } else {
        // Q/K cols: fused RoPE. Pair (d, d+32) = frags (j, j+2), same lane/
        // row. d = 16*jp + lm for jp in {0,1}. Q additionally scaled by
        // 0.125*log2e (log2-domain attention).
        const float qsc = (col0 < 2048) ? 0.125f * LOG2E : 1.0f;
        const float invf0 = exp2f(-(float)lm * L2THETA_32);          // d = lm
        const float invf1 = exp2f(-(float)(16 + lm) * L2THETA_32);   // d = 16+lm
#pragma unroll
        for (int i = 0; i < 2; ++i) {
            const int gr = row0 + wr + 16 * i + cr;
#pragma unroll
            for (int rr = 0; rr < 4; ++rr) {
                const float p = (float)pos[gr + rr];
                const float a0 = p * invf0, a1 = p * invf1;
                const float c0 = cosf(a0), s0 = sinf(a0);
                const float c1 = cosf(a1), s1 = sinf(a1);
                const float x00 = acc[i][0][rr], x02 = acc[i][2][rr];
                const float x01 = acc[i][1][rr], x03 = acc[i][3][rr];
                u16* outr = (u16*)Cv + (size_t)(gr + rr) * QKD + col0 + lm;
                outr[0]  = f2bf((x00 * c0 - x02 * s0) * qsc);
                outr[32] = f2bf((x02 * c0 + x00 * s0) * qsc);
                outr[16] = f2bf((x01 * c1 - x03 * s1) * qsc);
                outr[48] = f2bf((x03 * c1 + x01 * s1) * qsc);
            }
        }
    }
}

// ---------------------------------------------------------------------------
// MFMA flash attention (R12, unchanged): Q-tile 64, grid=(32 qtiles, 32
// heads) = 1024 blocks, 4 waves x one 16-row q-group, njt = qt+1 kv-tiles.
// Swizzled conflict-free layouts:
//   K: [64 kv][128B d]  V: [64 d][128B kv]  Q/P union: [64 q][128B]
// chunk' = chunk ^ (row&7) via pre-swizzled global source (LDS dest linear,
// rule 21); frag reads at fswz = (quad^(lm&7))<<4, second half fswz^64.
// vmcnt: Q(2 ops) + 4/stage -> Q-wait vmcnt(8) (vmcnt(4) if njt==1),
// acquire vmcnt(4)/(0). Scores log2-domain, fixed cap -16; row sums via
// ones-fragment MFMA.
// ---------------------------------------------------------------------------
__global__ __launch_bounds__(256)
void attn_mfma(const u16* __restrict__ QK, const u16* __restrict__ Vtg,
               u16* __restrict__ Ctx) {
    __shared__ __attribute__((aligned(16))) u16 QPs[4096];       // 8KB Q then P
    __shared__ __attribute__((aligned(16))) u16 Ks[2][4096];     // 2 x 8KB [64][128B]
    __shared__ __attribute__((aligned(16))) u16 Vts[2][4096];    // 2 x 8KB [64][128B]

    const int t = threadIdx.x;           // 0..255
    const int lane = t & 63;
    const int w = t >> 6;                // 0..3
    const int lm = lane & 15, quad = lane >> 4;
    const int qt = (gridDim.x - 1) - blockIdx.x;   // longest first (LPT)
    const int h = blockIdx.y;
    const int kh = h >> 2;
    const int q0 = qt * 64;
    const int njt = qt + 1;                        // kv tiles of 64

    const char* Kb = (const char*)(QK + 2048 + kh * HD);
    const char* Vb = (const char*)(Vtg + (size_t)(kh * 64) * S_LEN);

    // staging: thread t covers LDS rows srow and srow+32, chunk t&7;
    // source chunk pre-swizzled: chunk' = (t&7) ^ (row&7), row&7 == srow&7
    const int srow = t >> 3;                         // 0..31
    const int scswz = ((t & 7) ^ (srow & 7)) * 16;

    // stage Q: wave w stages its own rows [w*16, w*16+16) (2 vm ops;
    // read-set == staged-set per wave -> per-wave vmcnt wait is sufficient)
    {
        const char* qb = (const char*)(QK + h * HD);
        const int qrow = w * 16 + (lane >> 3);       // + k2*8; row&7 = lane>>3
        const int qcs = ((lane & 7) ^ (lane >> 3)) * 16;
#pragma unroll
        for (int k2 = 0; k2 < 2; ++k2)
            async_copy16((char*)QPs + w * 2048 + k2 * 1024 + lane * 16,
                         qb + (size_t)(q0 + qrow + k2 * 8) * (QKD * 2) + qcs);
    }

    auto stage_kv = [&](int jt_, int buf) {
        const int j0_ = jt_ * 64;
        char* kdst = (char*)Ks + buf * 8192 + t * 16;
        char* vdst = (char*)Vts + buf * 8192 + t * 16;
        async_copy16(kdst,        Kb + (size_t)(j0_ + srow)      * (QKD * 2) + scswz);
        async_copy16(kdst + 4096, Kb + (size_t)(j0_ + 32 + srow) * (QKD * 2) + scswz);
        async_copy16(vdst,        Vb + (size_t)srow        * (S_LEN * 2) + j0_ * 2 + scswz);
        async_copy16(vdst + 4096, Vb + (size_t)(32 + srow) * (S_LEN * 2) + j0_ * 2 + scswz);
    };

    stage_kv(0, 0);
    if (njt > 1) {
        stage_kv(1, 1);
        // wait for this wave's Q (2 oldest of 10); KV prefetches in flight
        asm volatile("s_waitcnt vmcnt(8)" ::: "memory");
    } else {
        // only Q(2) + kv0(4) outstanding -> Q done at vmcnt(4)
        asm volatile("s_waitcnt vmcnt(4)" ::: "memory");
    }

    // one-time Q fragment loads (B-operand: rows = q); swizzled read offset
    const int ra = w * 16 + lm;                      // ra&7 == lm&7
    const int fswz = ((quad ^ (lm & 7)) << 4);
    const short8 qa0 = *(const short8*)((const char*)QPs + ra * 128 + fswz);
    const short8 qa1 = *(const short8*)((const char*)QPs + ra * 128 + (fswz ^ 64));
    // drain Q reads before P writes alias the region (wave-private rows)
    asm volatile("s_waitcnt lgkmcnt(0)" ::: "memory");

    // constant ones A-frag: row m=0 (lanes with lm==0) = 1.0
    short8 onesf;
    {
        const short ob = (lm == 0) ? (short)0x3F80 : (short)0;
#pragma unroll
        for (int j = 0; j < 8; ++j) onesf[j] = ob;
    }

    f32x4 oa[4], la;
#pragma unroll
    for (int dt = 0; dt < 4; ++dt) oa[dt] = (f32x4){0.f, 0.f, 0.f, 0.f};
    la = (f32x4){0.f, 0.f, 0.f, 0.f};

    for (int jt = 0; jt < njt; ++jt) {
        const int cur = jt & 1;
        if (jt + 1 < njt) { asm volatile("s_waitcnt vmcnt(4)\ns_barrier" ::: "memory"); }
        else              { asm volatile("s_waitcnt vmcnt(0)\ns_barrier" ::: "memory"); }

        const char* Kc = (const char*)Ks + cur * 8192;
        const char* Vc = (const char*)Vts + cur * 8192;

        // S^T = K Q^T, log2 domain, cap -16
        f32x4 sa[4];
#pragma unroll
        for (int ct = 0; ct < 4; ++ct)
            sa[ct] = (f32x4){-16.f, -16.f, -16.f, -16.f};
#pragma unroll
        for (int ct = 0; ct < 4; ++ct) {
            const char* kr = Kc + (ct * 16 + lm) * 128;
            short8 kf0 = *(const short8*)(kr + fswz);
            short8 kf1 = *(const short8*)(kr + (fswz ^ 64));
            sa[ct] = __builtin_amdgcn_mfma_f32_16x16x32_bf16(kf0, qa0, sa[ct], 0, 0, 0);
            sa[ct] = __builtin_amdgcn_mfma_f32_16x16x32_bf16(kf1, qa1, sa[ct], 0, 0, 0);
        }
        // causal mask: only the diagonal tile (jt == qt)
        if (jt == qt) {
#pragma unroll
            for (int ct = 0; ct < 4; ++ct) {
                const int kvl = ct * 16 + quad * 4;
#pragma unroll
                for (int r = 0; r < 4; ++r)
                    if (kvl + r > ra) sa[ct][r] = -1e30f;
            }
        }
        // p = exp2(s); pack 4 kv -> one b64 swizzled LDS write per ct
#pragma unroll
        for (int ct = 0; ct < 4; ++ct) {
            ushort4 pka;
            pka.x = f2bf(__builtin_amdgcn_exp2f(sa[ct][0]));
            pka.y = f2bf(__builtin_amdgcn_exp2f(sa[ct][1]));
            pka.z = f2bf(__builtin_amdgcn_exp2f(sa[ct][2]));
            pka.w = f2bf(__builtin_amdgcn_exp2f(sa[ct][3]));
            const int pc = (((2 * ct + (quad >> 1)) ^ (lm & 7)) << 4) + ((quad & 1) << 3);
            *(ushort4*)((char*)QPs + ra * 128 + pc) = pka;
        }
        // P frags (wave-private rows, in-order LDS pipe); same fswz pattern
        const short8 pa0 = *(const short8*)((const char*)QPs + ra * 128 + fswz);
        const short8 pa1 = *(const short8*)((const char*)QPs + ra * 128 + (fswz ^ 64));
        // O^T += V^T P^T; l += ones . P
#pragma unroll
        for (int dt = 0; dt < 4; ++dt) {
            const char* vr = Vc + (dt * 16 + lm) * 128;
            short8 vf0 = *(const short8*)(vr + fswz);
            short8 vf1 = *(const short8*)(vr + (fswz ^ 64));
            oa[dt] = __builtin_amdgcn_mfma_f32_16x16x32_bf16(vf0, pa0, oa[dt], 0, 0, 0);
            oa[dt] = __builtin_amdgcn_mfma_f32_16x16x32_bf16(vf1, pa1, oa[dt], 0, 0, 0);
        }
        la = __builtin_amdgcn_mfma_f32_16x16x32_bf16(onesf, pa0, la, 0, 0, 0);
        la = __builtin_amdgcn_mfma_f32_16x16x32_bf16(onesf, pa1, la, 0, 0, 0);

        // all waves done reading buf[cur] -> safe to prefetch jt+2 into it
        asm volatile("s_waitcnt lgkmcnt(0)\ns_barrier" ::: "memory");
        if (jt + 2 < njt) stage_kv(jt + 2, cur);
    }

    // l for q-row ra lives in lane lm (quad 0), reg 0 -> broadcast
    const float inva = 1.f / __shfl(la[0], lm);
    const int rowa = q0 + ra;
#pragma unroll
    for (int dt = 0; dt < 4; ++dt) {
        ushort4 o;
        o.x = f2bf(oa[dt][0] * inva); o.y = f2bf(oa[dt][1] * inva);
        o.z = f2bf(oa[dt][2] * inva); o.w = f2bf(oa[dt][3] * inva);
        *(ushort4*)(Ctx + (size_t)rowa * HID + h * HD + dt * 16 + quad * 4) = o;
    }
}

// ---------------------------------------------------------------------------
extern "C" void kernel_launch(void* const* d_in, const int* in_sizes, int n_in,
                              void* d_out, int out_size, void* d_ws, size_t ws_size,
                              hipStream_t stream) {
    const float* X   = (const float*)d_in[0];
    const int*   pos = (const int*)d_in[1];
    const float* Wq  = (const float*)d_in[2];
    const float* Wk  = (const float*)d_in[3];
    const float* Wv  = (const float*)d_in[4];
    const float* Wo  = (const float*)d_in[5];
    float* out = (float*)d_out;

    // ws (bf16 elems): Xb 4M | WqkvT 6M | WoT 4M | QK 5M | Vt 1M  ~= 42 MB
    u16* Xb    = (u16*)d_ws;
    u16* WqkvT = Xb + (size_t)4194304;
    u16* WoT   = WqkvT + (size_t)6291456;
    u16* QK    = WoT + (size_t)4194304;
    u16* Vt    = QK + (size_t)S_LEN * QKD;
    u16* Ctxb  = Xb;   // Xb dead after QKV GEMM

    prep<<<dim3(64, 64, 5), 256, 0, stream>>>(X, Xb, Wq, Wk, Wv, Wo, WqkvT, WoT);

    gemm_bt<1><<<dim3(48, 16), 256, 0, stream>>>(Xb, WqkvT, QK, Vt, pos, 2048, 3072, 2048);

    attn_mfma<<<dim3(32, 32), 256, 0, stream>>>(QK, Vt, Ctxb);

    gemm_bt<0><<<dim3(32, 16), 256, 0, stream>>>(Ctxb, WoT, out, nullptr, pos, 2048, 2048, 2048);
}

// Round 7
// 204.624 us; speedup vs baseline: 1.2551x; 1.0698x over previous
//
#include <hip/hip_runtime.h>
#include <hip/hip_bf16.h>
#include <math.h>

#define S_LEN 2048
#define HID   2048
#define NH    32
#define NKV   8
#define HD    64
#define QKD   2560   // QK buffer row stride: Q[0:2048] | K[2048:2560]
#define LOG2E 1.44269504f
#define L2THETA_32 0.591611505f   // log2(500000)/32

typedef unsigned short u16;
typedef __attribute__((ext_vector_type(8))) short short8;   // 8 bf16 (MFMA A/B frag)
typedef __attribute__((ext_vector_type(4))) float f32x4;    // MFMA C/D frag

__device__ __forceinline__ u16 f2bf(float x) {
    union { __hip_bfloat16 b; u16 u; } c; c.b = __float2bfloat16(x); return c.u;
}
__device__ __forceinline__ float bf2f(u16 u) {
    union { unsigned int i; float f; } c; c.i = ((unsigned int)u) << 16; return c.f;
}
__device__ __forceinline__ void async_copy16(void* lds, const void* g) {
    __builtin_amdgcn_global_load_lds((const __attribute__((address_space(1))) unsigned int*)g,
                                     (__attribute__((address_space(3))) unsigned int*)lds,
                                     16, 0, 0);
}

// ---------------------------------------------------------------------------
// prep (R14): cast_bf16 + all four weight transposes in ONE dispatch.
// z 0..3 selects the weight transpose; z==4 is the X fp32->bf16 cast.
// ---------------------------------------------------------------------------
__global__ __launch_bounds__(256)
void prep(const float* __restrict__ X, u16* __restrict__ Xb,
          const float* __restrict__ Wq, const float* __restrict__ Wk,
          const float* __restrict__ Wv, const float* __restrict__ Wo,
          u16* __restrict__ WqkvT, u16* __restrict__ WoT) {
    if (blockIdx.z == 4) {
        // cast: 4.19M floats, 8 per thread; first 2048 of 4096 block slots
        const int i = (blockIdx.y * 64 + (int)blockIdx.x) * 256 + threadIdx.x;
        if (i >= 524288) return;
        const float4* p = (const float4*)(X + (size_t)i * 8);
        float4 a = p[0], b = p[1];
        short8 o;
        o[0] = f2bf(a.x); o[1] = f2bf(a.y); o[2] = f2bf(a.z); o[3] = f2bf(a.w);
        o[4] = f2bf(b.x); o[5] = f2bf(b.y); o[6] = f2bf(b.z); o[7] = f2bf(b.w);
        *(short8*)(Xb + (size_t)i * 8) = o;
        return;
    }
    const float* W; u16* WT; int Nin, xT;
    switch (blockIdx.z) {
        case 0:  W = Wq; WT = WqkvT;                         Nin = 2048; xT = 64; break;
        case 1:  W = Wk; WT = WqkvT + (size_t)2048 * 2048;   Nin = 512;  xT = 16; break;
        case 2:  W = Wv; WT = WqkvT + (size_t)2560 * 2048;   Nin = 512;  xT = 16; break;
        default: W = Wo; WT = WoT;                           Nin = 2048; xT = 64; break;
    }
    if ((int)blockIdx.x >= xT) return;
    __shared__ float tile[32][33];
    const int tx = threadIdx.x & 31, ty = threadIdx.x >> 5;
    const int x = blockIdx.x * 32 + tx;
#pragma unroll
    for (int j = ty; j < 32; j += 8)
        tile[j][tx] = W[(size_t)(blockIdx.y * 32 + j) * Nin + x];
    __syncthreads();
    const int xo = blockIdx.y * 32 + tx;
#pragma unroll
    for (int j = ty; j < 32; j += 8)
        WT[(size_t)(blockIdx.x * 32 + j) * 2048 + xo] = f2bf(tile[tx][j]);
}

// ---------------------------------------------------------------------------
// bf16 GEMM (R14): 256 threads / 4 waves, 128x64 tile, BK=64, double-buffered
// LDS, conflict-free swizzled 128B rows (chunk^(row&7), pre-swizzled global
// source + fswz frag reads). Grids divide 256 CUs exactly: gemm<1> 48x16=768
// (3.0/CU), gemm<0> 32x16=512 (2.0/CU). Staging 6 uniform ops/thread/stage,
// acquire vmcnt(6); 16 MFMAs/wave/stage; LDS 48KB -> 3 blocks/CU.
// MODE 0: fp32 C (stride N).
// MODE 1: QKV epilogue with FUSED RoPE (applied on fp32 acc before the bf16
// round; Q cols also get 0.125*LOG2E for log2-domain attention). cols >=
// 2560 -> V written TRANSPOSED to Vt[d][s].
// ---------------------------------------------------------------------------
template<int MODE>
__global__ __launch_bounds__(256)
void gemm_bt(const u16* __restrict__ A, const u16* __restrict__ Bt,
             void* __restrict__ Cv, u16* __restrict__ Vt,
             const int* __restrict__ pos, int M, int N, int K) {
    __shared__ __attribute__((aligned(16))) u16 As[2][8192];   // 2 x 16KB [128][128B]
    __shared__ __attribute__((aligned(16))) u16 Bs[2][4096];   // 2 x 8KB  [64][128B]
    const int t = threadIdx.x;           // 0..255
    const int lane = t & 63;
    const int w = t >> 6;                // 0..3
    const int lm = lane & 15, quad = lane >> 4;
    const int row0 = blockIdx.y * 128, col0 = blockIdx.x * 64;
    const int wr = w * 32;               // wave = 32 rows x 64 cols

    f32x4 acc[2][4];
#pragma unroll
    for (int i = 0; i < 2; ++i)
#pragma unroll
        for (int j = 0; j < 4; ++j) acc[i][j] = (f32x4){0.f, 0.f, 0.f, 0.f};

    const size_t strideB = (size_t)K * 2;
    const char* Ab = (const char*)(A + (size_t)row0 * K);
    const char* Bb = (const char*)(Bt + (size_t)col0 * K);

    // staging: thread t covers LDS rows {i*32 + t>>3}, chunk t&7 (8 x 16B
    // chunks per 128B row); source chunk pre-swizzled: (t&7) ^ (row&7)
    const int srow = t >> 3;                         // 0..31
    const int scswz = ((t & 7) ^ (srow & 7)) * 16;

    // one k-stage = 64 k: A 128x128B (4 ops) + B 64x128B (2 ops), uniform
    auto stage = [&](int ks, int buf) {
        const int k0b = ks * 128;        // byte offset along k
        char* ad = (char*)As[buf] + t * 16;
        char* bd = (char*)Bs[buf] + t * 16;
#pragma unroll
        for (int i = 0; i < 4; ++i)
            async_copy16(ad + i * 4096, Ab + (size_t)(i * 32 + srow) * strideB + k0b + scswz);
#pragma unroll
        for (int i = 0; i < 2; ++i)
            async_copy16(bd + i * 4096, Bb + (size_t)(i * 32 + srow) * strideB + k0b + scswz);
    };

    const int nk = K >> 6;
    stage(0, 0);
    if (nk > 1) stage(1, 1);

    const int fswz = (quad ^ (lm & 7)) << 4;

    for (int kk = 0; kk < nk; ++kk) {
        const int cur = kk & 1;
        // acquire: stage kk resident; stage kk+1 (6 ops) may stay in flight
        if (kk + 1 < nk) { asm volatile("s_waitcnt vmcnt(6)\ns_barrier" ::: "memory"); }
        else             { asm volatile("s_waitcnt vmcnt(0)\ns_barrier" ::: "memory"); }

        short8 af[2][2], bfv[4][2];
#pragma unroll
        for (int i = 0; i < 2; ++i) {
            const char* ar = (const char*)As[cur] + (wr + 16 * i + lm) * 128;
            af[i][0] = *(const short8*)(ar + fswz);
            af[i][1] = *(const short8*)(ar + (fswz ^ 64));
        }
#pragma unroll
        for (int j = 0; j < 4; ++j) {
            const char* br = (const char*)Bs[cur] + (16 * j + lm) * 128;
            bfv[j][0] = *(const short8*)(br + fswz);
            bfv[j][1] = *(const short8*)(br + (fswz ^ 64));
        }
#pragma unroll
        for (int i = 0; i < 2; ++i)
#pragma unroll
            for (int j = 0; j < 4; ++j) {
                acc[i][j] = __builtin_amdgcn_mfma_f32_16x16x32_bf16(af[i][0], bfv[j][0], acc[i][j], 0, 0, 0);
                acc[i][j] = __builtin_amdgcn_mfma_f32_16x16x32_bf16(af[i][1], bfv[j][1], acc[i][j], 0, 0, 0);
            }

        // release: frag reads drained -> safe to re-stage this buffer
        asm volatile("s_waitcnt lgkmcnt(0)\ns_barrier" ::: "memory");
        if (kk + 2 < nk) stage(kk + 2, cur);
    }

    // C/D layout: col = lane&15, row = quad*4 + reg  [m89-verified]
    const int cr = quad * 4;
    if (MODE == 0) {
#pragma unroll
        for (int i = 0; i < 2; ++i) {
            const int gr = row0 + wr + 16 * i + cr;
#pragma unroll
            for (int j = 0; j < 4; ++j) {
                const int gc = col0 + 16 * j + lm;
#pragma unroll
                for (int rr = 0; rr < 4; ++rr)
                    ((float*)Cv)[(size_t)(gr + rr) * N + gc] = acc[i][j][rr];
            }
        }
    } else if (col0 >= 2560) {
        // V written transposed to Vt[d][s]
#pragma unroll
        for (int i = 0; i < 2; ++i) {
            const int gr = row0 + wr + 16 * i + cr;
#pragma unroll
            for (int j = 0; j < 4; ++j) {
                const int d = col0 + 16 * j + lm - 2560;
                ushort4 vv;
                vv.x = f2bf(acc[i][j][0]); vv.y = f2bf(acc[i][j][1]);
                vv.z = f2bf(acc[i][j][2]); vv.w = f2bf(acc[i][j][3]);
                *(ushort4*)(Vt + (size_t)d * S_LEN + gr) = vv;
            }
        }
    } else {
        // Q/K cols: fused RoPE. Pair (d, d+32) = frags (j, j+2), same lane/
        // row. d = 16*jp + lm for jp in {0,1}. Q additionally scaled by
        // 0.125*log2e (log2-domain attention).
        const float qsc = (col0 < 2048) ? 0.125f * LOG2E : 1.0f;
        const float invf0 = exp2f(-(float)lm * L2THETA_32);          // d = lm
        const float invf1 = exp2f(-(float)(16 + lm) * L2THETA_32);   // d = 16+lm
#pragma unroll
        for (int i = 0; i < 2; ++i) {
            const int gr = row0 + wr + 16 * i + cr;
#pragma unroll
            for (int rr = 0; rr < 4; ++rr) {
                const float p = (float)pos[gr + rr];
                const float a0 = p * invf0, a1 = p * invf1;
                const float c0 = cosf(a0), s0 = sinf(a0);
                const float c1 = cosf(a1), s1 = sinf(a1);
                const float x00 = acc[i][0][rr], x02 = acc[i][2][rr];
                const float x01 = acc[i][1][rr], x03 = acc[i][3][rr];
                u16* outr = (u16*)Cv + (size_t)(gr + rr) * QKD + col0 + lm;
                outr[0]  = f2bf((x00 * c0 - x02 * s0) * qsc);
                outr[32] = f2bf((x02 * c0 + x00 * s0) * qsc);
                outr[16] = f2bf((x01 * c1 - x03 * s1) * qsc);
                outr[48] = f2bf((x03 * c1 + x01 * s1) * qsc);
            }
        }
    }
}

// ---------------------------------------------------------------------------
// MFMA flash attention (R15): R12 structure + LOAD-BALANCED qt mapping.
// Diagnosis: 1024 blocks = exactly 4/CU all resident at t=0; any 256-periodic
// block->CU assignment gives CU c the blocks {c, c+256, c+512, c+768}, which
// share blockIdx.x%32 — i.e. the SAME qt four times. Worst CU did 4x32=128
// jt-units vs 66 avg (1.94x imbalance) -> kernel time = straggler CU. Fix:
// qt = (bx + h) & 31 (bijective per head). Co-resident blocks then have h
// spaced by 8 -> qt spaced {0,8,16,24} -> per-CU load in [52,80] jt
// (max/avg 1.21). Everything else identical to R12:
//   K: [64 kv][128B d]  V: [64 d][128B kv]  Q/P union: [64 q][128B]
// chunk' = chunk ^ (row&7) pre-swizzled source; frag reads fswz/(fswz^64).
// vmcnt: Q-wait vmcnt(8) (vmcnt(4) if njt==1), acquire vmcnt(4)/(0).
// ---------------------------------------------------------------------------
__global__ __launch_bounds__(256)
void attn_mfma(const u16* __restrict__ QK, const u16* __restrict__ Vtg,
               u16* __restrict__ Ctx) {
    __shared__ __attribute__((aligned(16))) u16 QPs[4096];       // 8KB Q then P
    __shared__ __attribute__((aligned(16))) u16 Ks[2][4096];     // 2 x 8KB [64][128B]
    __shared__ __attribute__((aligned(16))) u16 Vts[2][4096];    // 2 x 8KB [64][128B]

    const int t = threadIdx.x;           // 0..255
    const int lane = t & 63;
    const int w = t >> 6;                // 0..3
    const int lm = lane & 15, quad = lane >> 4;
    const int h = blockIdx.y;
    const int qt = ((int)blockIdx.x + h) & 31;     // balanced qt per CU
    const int kh = h >> 2;
    const int q0 = qt * 64;
    const int njt = qt + 1;                        // kv tiles of 64

    const char* Kb = (const char*)(QK + 2048 + kh * HD);
    const char* Vb = (const char*)(Vtg + (size_t)(kh * 64) * S_LEN);

    // staging: thread t covers LDS rows srow and srow+32, chunk t&7;
    // source chunk pre-swizzled: chunk' = (t&7) ^ (row&7), row&7 == srow&7
    const int srow = t >> 3;                         // 0..31
    const int scswz = ((t & 7) ^ (srow & 7)) * 16;

    // stage Q: wave w stages its own rows [w*16, w*16+16) (2 vm ops;
    // read-set == staged-set per wave -> per-wave vmcnt wait is sufficient)
    {
        const char* qb = (const char*)(QK + h * HD);
        const int qrow = w * 16 + (lane >> 3);       // + k2*8; row&7 = lane>>3
        const int qcs = ((lane & 7) ^ (lane >> 3)) * 16;
#pragma unroll
        for (int k2 = 0; k2 < 2; ++k2)
            async_copy16((char*)QPs + w * 2048 + k2 * 1024 + lane * 16,
                         qb + (size_t)(q0 + qrow + k2 * 8) * (QKD * 2) + qcs);
    }

    auto stage_kv = [&](int jt_, int buf) {
        const int j0_ = jt_ * 64;
        char* kdst = (char*)Ks + buf * 8192 + t * 16;
        char* vdst = (char*)Vts + buf * 8192 + t * 16;
        async_copy16(kdst,        Kb + (size_t)(j0_ + srow)      * (QKD * 2) + scswz);
        async_copy16(kdst + 4096, Kb + (size_t)(j0_ + 32 + srow) * (QKD * 2) + scswz);
        async_copy16(vdst,        Vb + (size_t)srow        * (S_LEN * 2) + j0_ * 2 + scswz);
        async_copy16(vdst + 4096, Vb + (size_t)(32 + srow) * (S_LEN * 2) + j0_ * 2 + scswz);
    };

    stage_kv(0, 0);
    if (njt > 1) {
        stage_kv(1, 1);
        // wait for this wave's Q (2 oldest of 10); KV prefetches in flight
        asm volatile("s_waitcnt vmcnt(8)" ::: "memory");
    } else {
        // only Q(2) + kv0(4) outstanding -> Q done at vmcnt(4)
        asm volatile("s_waitcnt vmcnt(4)" ::: "memory");
    }

    // one-time Q fragment loads (B-operand: rows = q); swizzled read offset
    const int ra = w * 16 + lm;                      // ra&7 == lm&7
    const int fswz = ((quad ^ (lm & 7)) << 4);
    const short8 qa0 = *(const short8*)((const char*)QPs + ra * 128 + fswz);
    const short8 qa1 = *(const short8*)((const char*)QPs + ra * 128 + (fswz ^ 64));
    // drain Q reads before P writes alias the region (wave-private rows)
    asm volatile("s_waitcnt lgkmcnt(0)" ::: "memory");

    // constant ones A-frag: row m=0 (lanes with lm==0) = 1.0
    short8 onesf;
    {
        const short ob = (lm == 0) ? (short)0x3F80 : (short)0;
#pragma unroll
        for (int j = 0; j < 8; ++j) onesf[j] = ob;
    }

    f32x4 oa[4], la;
#pragma unroll
    for (int dt = 0; dt < 4; ++dt) oa[dt] = (f32x4){0.f, 0.f, 0.f, 0.f};
    la = (f32x4){0.f, 0.f, 0.f, 0.f};

    for (int jt = 0; jt < njt; ++jt) {
        const int cur = jt & 1;
        if (jt + 1 < njt) { asm volatile("s_waitcnt vmcnt(4)\ns_barrier" ::: "memory"); }
        else              { asm volatile("s_waitcnt vmcnt(0)\ns_barrier" ::: "memory"); }

        const char* Kc = (const char*)Ks + cur * 8192;
        const char* Vc = (const char*)Vts + cur * 8192;

        // S^T = K Q^T, log2 domain, cap -16
        f32x4 sa[4];
#pragma unroll
        for (int ct = 0; ct < 4; ++ct)
            sa[ct] = (f32x4){-16.f, -16.f, -16.f, -16.f};
#pragma unroll
        for (int ct = 0; ct < 4; ++ct) {
            const char* kr = Kc + (ct * 16 + lm) * 128;
            short8 kf0 = *(const short8*)(kr + fswz);
            short8 kf1 = *(const short8*)(kr + (fswz ^ 64));
            sa[ct] = __builtin_amdgcn_mfma_f32_16x16x32_bf16(kf0, qa0, sa[ct], 0, 0, 0);
            sa[ct] = __builtin_amdgcn_mfma_f32_16x16x32_bf16(kf1, qa1, sa[ct], 0, 0, 0);
        }
        // causal mask: only the diagonal tile (jt == qt)
        if (jt == qt) {
#pragma unroll
            for (int ct = 0; ct < 4; ++ct) {
                const int kvl = ct * 16 + quad * 4;
#pragma unroll
                for (int r = 0; r < 4; ++r)
                    if (kvl + r > ra) sa[ct][r] = -1e30f;
            }
        }
        // p = exp2(s); pack 4 kv -> one b64 swizzled LDS write per ct
#pragma unroll
        for (int ct = 0; ct < 4; ++ct) {
            ushort4 pka;
            pka.x = f2bf(__builtin_amdgcn_exp2f(sa[ct][0]));
            pka.y = f2bf(__builtin_amdgcn_exp2f(sa[ct][1]));
            pka.z = f2bf(__builtin_amdgcn_exp2f(sa[ct][2]));
            pka.w = f2bf(__builtin_amdgcn_exp2f(sa[ct][3]));
            const int pc = (((2 * ct + (quad >> 1)) ^ (lm & 7)) << 4) + ((quad & 1) << 3);
            *(ushort4*)((char*)QPs + ra * 128 + pc) = pka;
        }
        // P frags (wave-private rows, in-order LDS pipe); same fswz pattern
        const short8 pa0 = *(const short8*)((const char*)QPs + ra * 128 + fswz);
        const short8 pa1 = *(const short8*)((const char*)QPs + ra * 128 + (fswz ^ 64));
        // O^T += V^T P^T; l += ones . P
#pragma unroll
        for (int dt = 0; dt < 4; ++dt) {
            const char* vr = Vc + (dt * 16 + lm) * 128;
            short8 vf0 = *(const short8*)(vr + fswz);
            short8 vf1 = *(const short8*)(vr + (fswz ^ 64));
            oa[dt] = __builtin_amdgcn_mfma_f32_16x16x32_bf16(vf0, pa0, oa[dt], 0, 0, 0);
            oa[dt] = __builtin_amdgcn_mfma_f32_16x16x32_bf16(vf1, pa1, oa[dt], 0, 0, 0);
        }
        la = __builtin_amdgcn_mfma_f32_16x16x32_bf16(onesf, pa0, la, 0, 0, 0);
        la = __builtin_amdgcn_mfma_f32_16x16x32_bf16(onesf, pa1, la, 0, 0, 0);

        // all waves done reading buf[cur] -> safe to prefetch jt+2 into it
        asm volatile("s_waitcnt lgkmcnt(0)\ns_barrier" ::: "memory");
        if (jt + 2 < njt) stage_kv(jt + 2, cur);
    }

    // l for q-row ra lives in lane lm (quad 0), reg 0 -> broadcast
    const float inva = 1.f / __shfl(la[0], lm);
    const int rowa = q0 + ra;
#pragma unroll
    for (int dt = 0; dt < 4; ++dt) {
        ushort4 o;
        o.x = f2bf(oa[dt][0] * inva); o.y = f2bf(oa[dt][1] * inva);
        o.z = f2bf(oa[dt][2] * inva); o.w = f2bf(oa[dt][3] * inva);
        *(ushort4*)(Ctx + (size_t)rowa * HID + h * HD + dt * 16 + quad * 4) = o;
    }
}

// ---------------------------------------------------------------------------
extern "C" void kernel_launch(void* const* d_in, const int* in_sizes, int n_in,
                              void* d_out, int out_size, void* d_ws, size_t ws_size,
                              hipStream_t stream) {
    const float* X   = (const float*)d_in[0];
    const int*   pos = (const int*)d_in[1];
    const float* Wq  = (const float*)d_in[2];
    const float* Wk  = (const float*)d_in[3];
    const float* Wv  = (const float*)d_in[4];
    const float* Wo  = (const float*)d_in[5];
    float* out = (float*)d_out;

    // ws (bf16 elems): Xb 4M | WqkvT 6M | WoT 4M | QK 5M | Vt 1M  ~= 42 MB
    u16* Xb    = (u16*)d_ws;
    u16* WqkvT = Xb + (size_t)4194304;
    u16* WoT   = WqkvT + (size_t)6291456;
    u16* QK    = WoT + (size_t)4194304;
    u16* Vt    = QK + (size_t)S_LEN * QKD;
    u16* Ctxb  = Xb;   // Xb dead after QKV GEMM

    prep<<<dim3(64, 64, 5), 256, 0, stream>>>(X, Xb, Wq, Wk, Wv, Wo, WqkvT, WoT);

    gemm_bt<1><<<dim3(48, 16), 256, 0, stream>>>(Xb, WqkvT, QK, Vt, pos, 2048, 3072, 2048);

    attn_mfma<<<dim3(32, 32), 256, 0, stream>>>(QK, Vt, Ctxb);

    gemm_bt<0><<<dim3(32, 16), 256, 0, stream>>>(Ctxb, WoT, out, nullptr, pos, 2048, 2048, 2048);
}